// Round 31
// baseline (205.103 us; speedup 1.0000x reference)
//
#include <hip/hip_runtime.h>
#include <hip/hip_bf16.h>
#include <stdint.h>

typedef __bf16 bf16_4 __attribute__((ext_vector_type(4)));
typedef __bf16 bf16_8 __attribute__((ext_vector_type(8)));
typedef float f32x4 __attribute__((ext_vector_type(4)));

#define AS1 __attribute__((address_space(1)))
#define AS3 __attribute__((address_space(3)))

__device__ __forceinline__ void gload_lds16(const void* g, void* l) {
  __builtin_amdgcn_global_load_lds((const AS1 void*)g, (AS3 void*)l, 16, 0, 0);
}

// isb: device-side dtype probe. cos[0] == 1.0 exactly; f32 1.0 low halfword =
// 0x0000, packed bf16 (1.0,1.0) = 0x3F803F80 -> low halfword 0x3F80.
__device__ __forceinline__ bool is_bf16_mode(const void* cosT) {
  return ((*reinterpret_cast<const uint32_t*>(cosT)) & 0xFFFFu) == 0x3F80u;
}

// ---------------------------------------------------------------------------
// Fused prep: [0,512) cos/sin->f32; [512,4608) x->bf16 (f32 mode ONLY — in
// bf16 mode gemm1 reads x directly); [4608,9728) weight transpose+convert,
// VECTORIZED: 64x32 tiles, one 16B load + one 16B store per thread.
// ---------------------------------------------------------------------------
__global__ __launch_bounds__(256) void prep_all(const void* __restrict__ cosT,
                                                const void* __restrict__ sinT,
                                                const void* __restrict__ x,
                                                const void* __restrict__ WQ,
                                                const void* __restrict__ WK,
                                                const void* __restrict__ WV,
                                                const void* __restrict__ WO,
                                                float* __restrict__ csF,
                                                __bf16* __restrict__ xb,
                                                __bf16* __restrict__ Wt,
                                                __bf16* __restrict__ WOt) {
  const int blk = blockIdx.x, tid = threadIdx.x;
  const bool isb = is_bf16_mode(cosT);
  if (blk < 512) {                      // tables -> f32
    const int i = blk * 256 + tid;
    if (isb) {
      csF[i]          = (float)reinterpret_cast<const __bf16*>(cosT)[i];
      csF[131072 + i] = (float)reinterpret_cast<const __bf16*>(sinT)[i];
    } else {
      csF[i]          = reinterpret_cast<const float*>(cosT)[i];
      csF[131072 + i] = reinterpret_cast<const float*>(sinT)[i];
    }
    return;
  }
  if (blk < 4608) {                     // x -> bf16 (f32 mode only)
    if (isb) return;                    // bf16 mode: gemm reads x directly
    const int i = (blk - 512) * 256 + tid;
    const float4* s = reinterpret_cast<const float4*>(x);
    const float4 a = s[2 * i], c = s[2 * i + 1];
    __bf16 o[8] = {(__bf16)a.x, (__bf16)a.y, (__bf16)a.z, (__bf16)a.w,
                   (__bf16)c.x, (__bf16)c.y, (__bf16)c.z, (__bf16)c.w};
    reinterpret_cast<int4*>(xb)[i] = *reinterpret_cast<int4*>(o);
    return;
  }
  // weight transpose: tb in [0,5120) = (bx 0..159) x (by 0..31), 64x32 tile
  __shared__ __bf16 t[64][33];          // +1 pad: column reads stride 33 = CF
  const int tb = blk - 4608;
  const int bx = tb % 160, by = tb / 160;
  const void* src;
  __bf16* dst;
  int C, c0;
  if (bx < 64)      { src = WQ; dst = Wt;                        C = 2048; c0 = bx * 32; }
  else if (bx < 80) { src = WK; dst = Wt + (size_t)2048 * 2048;  C = 512;  c0 = (bx - 64) * 32; }
  else if (bx < 96) { src = WV; dst = Wt + (size_t)2560 * 2048;  C = 512;  c0 = (bx - 80) * 32; }
  else              { src = WO; dst = WOt;                       C = 2048; c0 = (bx - 96) * 32; }
  const int r0 = by * 64;
  // load: thread -> (row = tid>>2, colblk = (tid&3)*8), one 16B (bf16) or
  // 2x16B (f32) vector load, 8 LDS scalar writes
  {
    const int row = tid >> 2, cb = (tid & 3) * 8;
    bf16_8 v;
    if (isb) {
      v = *reinterpret_cast<const bf16_8*>(
          reinterpret_cast<const __bf16*>(src) + (size_t)(r0 + row) * C + c0 + cb);
    } else {
      const float* sp = reinterpret_cast<const float*>(src) + (size_t)(r0 + row) * C + c0 + cb;
      const float4 a = *reinterpret_cast<const float4*>(sp);
      const float4 b2 = *reinterpret_cast<const float4*>(sp + 4);
      v[0] = (__bf16)a.x;  v[1] = (__bf16)a.y;  v[2] = (__bf16)a.z;  v[3] = (__bf16)a.w;
      v[4] = (__bf16)b2.x; v[5] = (__bf16)b2.y; v[6] = (__bf16)b2.z; v[7] = (__bf16)b2.w;
    }
    #pragma unroll
    for (int k = 0; k < 8; ++k) t[row][cb + k] = v[k];
  }
  __syncthreads();
  // store: thread -> (out col j = tid>>3, row seg = (tid&7)*8), 8 LDS column
  // reads (stride 33, conflict-free) -> one 16B vector store
  {
    const int j = tid >> 3, seg = (tid & 7) * 8;
    bf16_8 v;
    #pragma unroll
    for (int k = 0; k < 8; ++k) v[k] = t[seg + k][j];
    *reinterpret_cast<bf16_8*>(dst + (size_t)(c0 + j) * 2048 + r0 + seg) = v;
  }
}

// ---------------------------------------------------------------------------
// GEMM A: 128x256 tile, BK=64, 8 waves, dbuf LDS (96KB), XOR-swizzle,
// 2 phases/K-tile, counted vmcnt + setprio. 1-D grid, bijective XCD swizzle.
// Output dtype per is_bf16_mode(cosRaw). Used for gemm2 (N=2048, grid 256).
// ---------------------------------------------------------------------------
__global__ __launch_bounds__(512) void gemm8p(const __bf16* __restrict__ A,
                                              const __bf16* __restrict__ Bt,
                                              void* __restrict__ Cv,
                                              int M, int N, int K,
                                              const void* __restrict__ cosRaw) {
  __shared__ __attribute__((aligned(16))) __bf16 As[2][128 * 64];
  __shared__ __attribute__((aligned(16))) __bf16 Bs[2][256 * 64];
  const int tid = threadIdx.x;
  const int lane = tid & 63, w = tid >> 6;
  const int wm = w >> 2, wn = w & 3;
  const int r = lane & 15, g = lane >> 4;
  const int q8 = gridDim.x >> 3;
  const int wg = (blockIdx.x & 7) * q8 + (blockIdx.x >> 3);
  const int gx = M >> 7;
  const int bm = (wg % gx) * 128, bn = (wg / gx) * 256;
  const bool isb = is_bf16_mode(cosRaw);
  const int NT = K >> 6;

  f32x4 acc[4][4] = {};

#define STA(kt, p, j)                                                              \
  {                                                                                \
    const int o_ = tid * 16 + (j) * 8192;                                          \
    const int row_ = o_ >> 7, blk_ = (o_ >> 4) & 7;                                \
    gload_lds16(A + (size_t)(bm + row_) * K + (kt) * 64 + ((blk_ ^ (row_ & 7)) << 3), \
                (char*)As[p] + o_);                                                \
  }
#define STB(kt, p, j)                                                              \
  {                                                                                \
    const int o_ = tid * 16 + (j) * 8192;                                          \
    const int rl_ = o_ >> 7, blk_ = (o_ >> 4) & 7;                                 \
    const int gr_ = ((rl_ >> 5) & 3) * 64 + ((rl_ >> 7) & 1) * 32 + (rl_ & 31);    \
    gload_lds16(Bt + (size_t)(bn + gr_) * K + (kt) * 64 + ((blk_ ^ (rl_ & 7)) << 3), \
                (char*)Bs[p] + o_);                                                \
  }

  STA(0, 0, 0); STA(0, 0, 1);
  STB(0, 0, 0); STB(0, 0, 1); STB(0, 0, 2); STB(0, 0, 3);
  asm volatile("s_waitcnt vmcnt(2)\ns_barrier" ::: "memory");

  for (int kt = 0; kt < NT; ++kt) {
    const int cur = kt & 1, nxt = cur ^ 1;
    const bool pf = (kt + 1 < NT);
    const char* Ac = (const char*)As[cur];
    const char* Bc = (const char*)Bs[cur];

    bf16_8 af[4][2], bf[2][2];
    #pragma unroll
    for (int m = 0; m < 4; ++m)
      #pragma unroll
      for (int kk = 0; kk < 2; ++kk) {
        const int row = wm * 64 + m * 16 + r;
        af[m][kk] = *reinterpret_cast<const bf16_8*>(
            Ac + row * 128 + (((kk * 4 + g) ^ (row & 7)) << 4));
      }
    #pragma unroll
    for (int n = 0; n < 2; ++n)
      #pragma unroll
      for (int kk = 0; kk < 2; ++kk) {
        const int rl = wn * 32 + n * 16 + r;
        bf[n][kk] = *reinterpret_cast<const bf16_8*>(
            Bc + rl * 128 + (((kk * 4 + g) ^ (rl & 7)) << 4));
      }
    if (pf) { STA(kt + 1, nxt, 0); STA(kt + 1, nxt, 1); STB(kt + 1, nxt, 0); }
    __builtin_amdgcn_s_barrier();
    __builtin_amdgcn_s_setprio(1);
    #pragma unroll
    for (int kk = 0; kk < 2; ++kk)
      #pragma unroll
      for (int m = 0; m < 4; ++m)
        #pragma unroll
        for (int n = 0; n < 2; ++n)
          acc[m][n] = __builtin_amdgcn_mfma_f32_16x16x32_bf16(af[m][kk], bf[n][kk], acc[m][n], 0, 0, 0);
    __builtin_amdgcn_s_setprio(0);
    if (pf) asm volatile("s_waitcnt vmcnt(3)\ns_barrier" ::: "memory");
    else    asm volatile("s_waitcnt vmcnt(0)\ns_barrier" ::: "memory");

    bf16_8 bg[2][2];
    #pragma unroll
    for (int n = 0; n < 2; ++n)
      #pragma unroll
      for (int kk = 0; kk < 2; ++kk) {
        const int rl = 128 + wn * 32 + n * 16 + r;
        bg[n][kk] = *reinterpret_cast<const bf16_8*>(
            Bc + rl * 128 + (((kk * 4 + g) ^ (rl & 7)) << 4));
      }
    if (pf) { STB(kt + 1, nxt, 1); STB(kt + 1, nxt, 2); STB(kt + 1, nxt, 3); }
    __builtin_amdgcn_s_barrier();
    __builtin_amdgcn_s_setprio(1);
    #pragma unroll
    for (int kk = 0; kk < 2; ++kk)
      #pragma unroll
      for (int m = 0; m < 4; ++m)
        #pragma unroll
        for (int n = 0; n < 2; ++n)
          acc[m][n + 2] = __builtin_amdgcn_mfma_f32_16x16x32_bf16(af[m][kk], bg[n][kk], acc[m][n + 2], 0, 0, 0);
    __builtin_amdgcn_s_setprio(0);
    if (pf) asm volatile("s_waitcnt vmcnt(2)\ns_barrier" ::: "memory");
    else    asm volatile("s_waitcnt vmcnt(0)\ns_barrier" ::: "memory");
  }
#undef STA
#undef STB

  #pragma unroll
  for (int m = 0; m < 4; ++m)
    #pragma unroll
    for (int n = 0; n < 4; ++n)
      #pragma unroll
      for (int j = 0; j < 4; ++j) {
        const int row = bm + wm * 64 + m * 16 + g * 4 + j;
        const int col = bn + wn * 64 + n * 16 + r;
        const float v = acc[m][n][j];
        if (isb) reinterpret_cast<__bf16*>(Cv)[(size_t)row * N + col] = (__bf16)v;
        else     reinterpret_cast<float*>(Cv)[(size_t)row * N + col] = v;
      }
}

// ---------------------------------------------------------------------------
// GEMM B: 128x384 tile for N=3072 -> grid 256 = 1 block/CU exactly.
// 3 phases/K-tile, counted-vmcnt ledger. A operand: bf16 mode reads x
// directly (Araw). V outputs (col >= 2560, bf16 mode) go directly to VT
// in transposed layout (packed 8B store); f32 mode keeps the old path.
// ---------------------------------------------------------------------------
__global__ __launch_bounds__(512) void gemm8p3(const __bf16* __restrict__ Acvt,
                                               const void* __restrict__ Araw,
                                               const __bf16* __restrict__ Bt,
                                               __bf16* __restrict__ Cv,
                                               __bf16* __restrict__ vtOut,
                                               int M, int N, int K,
                                               const void* __restrict__ cosRaw) {
  __shared__ __attribute__((aligned(16))) __bf16 As[2][128 * 64];
  __shared__ __attribute__((aligned(16))) __bf16 Bs[2][384 * 64];
  const int tid = threadIdx.x;
  const int lane = tid & 63, w = tid >> 6;
  const int wm = w >> 2, wn = w & 3;
  const int r = lane & 15, g = lane >> 4;
  const int q8 = gridDim.x >> 3;
  const int wg = (blockIdx.x & 7) * q8 + (blockIdx.x >> 3);
  const int gx = M >> 7;
  const int bm = (wg % gx) * 128, bn = (wg / gx) * 384;
  const int NT = K >> 6;
  const bool isb = is_bf16_mode(cosRaw);
  const __bf16* A = isb ? (const __bf16*)Araw : Acvt;

  f32x4 acc[4][6] = {};

#define STA3(kt, p, j)                                                             \
  {                                                                                \
    const int o_ = tid * 16 + (j) * 8192;                                          \
    const int row_ = o_ >> 7, blk_ = (o_ >> 4) & 7;                                \
    gload_lds16(A + (size_t)(bm + row_) * K + (kt) * 64 + ((blk_ ^ (row_ & 7)) << 3), \
                (char*)As[p] + o_);                                                \
  }
#define STB3(kt, p, j)                                                             \
  {                                                                                \
    const int o_ = tid * 16 + (j) * 8192;                                          \
    const int rl_ = o_ >> 7, blk_ = (o_ >> 4) & 7;                                 \
    const int gr_ = ((rl_ & 127) >> 5) * 96 + (rl_ >> 7) * 32 + (rl_ & 31);        \
    gload_lds16(Bt + (size_t)(bn + gr_) * K + (kt) * 64 + ((blk_ ^ (rl_ & 7)) << 3), \
                (char*)Bs[p] + o_);                                                \
  }

  STA3(0, 0, 0); STA3(0, 0, 1);
  STB3(0, 0, 0); STB3(0, 0, 1); STB3(0, 0, 2);
  STB3(0, 0, 3); STB3(0, 0, 4); STB3(0, 0, 5);
  asm volatile("s_waitcnt vmcnt(4)\ns_barrier" ::: "memory");

  for (int kt = 0; kt < NT; ++kt) {
    const int cur = kt & 1, nxt = cur ^ 1;
    const bool pf = (kt + 1 < NT);
    const char* Ac = (const char*)As[cur];
    const char* Bc = (const char*)Bs[cur];
    bf16_8 af[4][2];

    // ---- phase A: all A-frags + B seg0 (n = 0,1) ----
    {
      #pragma unroll
      for (int m = 0; m < 4; ++m)
        #pragma unroll
        for (int kk = 0; kk < 2; ++kk) {
          const int row = wm * 64 + m * 16 + r;
          af[m][kk] = *reinterpret_cast<const bf16_8*>(
              Ac + row * 128 + (((kk * 4 + g) ^ (row & 7)) << 4));
        }
      bf16_8 bf[2][2];
      #pragma unroll
      for (int n = 0; n < 2; ++n)
        #pragma unroll
        for (int kk = 0; kk < 2; ++kk) {
          const int rl = wn * 32 + n * 16 + r;
          bf[n][kk] = *reinterpret_cast<const bf16_8*>(
              Bc + rl * 128 + (((kk * 4 + g) ^ (r & 7)) << 4));
        }
      if (pf) { STA3(kt + 1, nxt, 0); STA3(kt + 1, nxt, 1); STB3(kt + 1, nxt, 0); }
      __builtin_amdgcn_s_barrier();
      __builtin_amdgcn_s_setprio(1);
      #pragma unroll
      for (int kk = 0; kk < 2; ++kk)
        #pragma unroll
        for (int m = 0; m < 4; ++m)
          #pragma unroll
          for (int n = 0; n < 2; ++n)
            acc[m][n] = __builtin_amdgcn_mfma_f32_16x16x32_bf16(af[m][kk], bf[n][kk], acc[m][n], 0, 0, 0);
      __builtin_amdgcn_s_setprio(0);
      if (pf) asm volatile("s_waitcnt vmcnt(5)\ns_barrier" ::: "memory");
      else    asm volatile("s_waitcnt vmcnt(0)\ns_barrier" ::: "memory");
    }

    // ---- phase B: B seg1 (n = 2,3) ----
    {
      bf16_8 bf[2][2];
      #pragma unroll
      for (int n = 0; n < 2; ++n)
        #pragma unroll
        for (int kk = 0; kk < 2; ++kk) {
          const int rl = 128 + wn * 32 + n * 16 + r;
          bf[n][kk] = *reinterpret_cast<const bf16_8*>(
              Bc + rl * 128 + (((kk * 4 + g) ^ (r & 7)) << 4));
        }
      if (pf) { STB3(kt + 1, nxt, 1); STB3(kt + 1, nxt, 2); }
      __builtin_amdgcn_s_barrier();
      __builtin_amdgcn_s_setprio(1);
      #pragma unroll
      for (int kk = 0; kk < 2; ++kk)
        #pragma unroll
        for (int m = 0; m < 4; ++m)
          #pragma unroll
          for (int n = 0; n < 2; ++n)
            acc[m][n + 2] = __builtin_amdgcn_mfma_f32_16x16x32_bf16(af[m][kk], bf[n][kk], acc[m][n + 2], 0, 0, 0);
      __builtin_amdgcn_s_setprio(0);
      if (pf) asm volatile("s_waitcnt vmcnt(5)\ns_barrier" ::: "memory");
      else    asm volatile("s_waitcnt vmcnt(0)\ns_barrier" ::: "memory");
    }

    // ---- phase C: B seg2 (n = 4,5) ----
    {
      bf16_8 bf[2][2];
      #pragma unroll
      for (int n = 0; n < 2; ++n)
        #pragma unroll
        for (int kk = 0; kk < 2; ++kk) {
          const int rl = 256 + wn * 32 + n * 16 + r;
          bf[n][kk] = *reinterpret_cast<const bf16_8*>(
              Bc + rl * 128 + (((kk * 4 + g) ^ (r & 7)) << 4));
        }
      if (pf) { STB3(kt + 1, nxt, 3); STB3(kt + 1, nxt, 4); STB3(kt + 1, nxt, 5); }
      __builtin_amdgcn_s_barrier();
      __builtin_amdgcn_s_setprio(1);
      #pragma unroll
      for (int kk = 0; kk < 2; ++kk)
        #pragma unroll
        for (int m = 0; m < 4; ++m)
          #pragma unroll
          for (int n = 0; n < 2; ++n)
            acc[m][n + 4] = __builtin_amdgcn_mfma_f32_16x16x32_bf16(af[m][kk], bf[n][kk], acc[m][n + 4], 0, 0, 0);
      __builtin_amdgcn_s_setprio(0);
      if (pf) asm volatile("s_waitcnt vmcnt(4)\ns_barrier" ::: "memory");
      else    asm volatile("s_waitcnt vmcnt(0)\ns_barrier" ::: "memory");
    }
  }
#undef STA3
#undef STB3

  #pragma unroll
  for (int m = 0; m < 4; ++m)
    #pragma unroll
    for (int n = 0; n < 6; ++n) {
      const int row0 = bm + wm * 64 + m * 16 + g * 4;   // 4-aligned, +j rows
      const int col  = bn + wn * 96 + n * 16 + r;
      if (isb && col >= 2560) {
        // V output -> VT[b][kvh][d][t0..t0+3], one packed 8B store
        const int vcol = col - 2560;                    // 0..511 = kvh*128+d
        const int bb = row0 >> 11;                      // batch index
        const int t0 = row0 & 2047;                     // 4-aligned
        bf16_4 pk;
        #pragma unroll
        for (int j = 0; j < 4; ++j) pk[j] = (__bf16)acc[m][n][j];
        *reinterpret_cast<bf16_4*>(
            &vtOut[((size_t)bb * 512 + vcol) * 2048 + t0]) = pk;
      } else {
        #pragma unroll
        for (int j = 0; j < 4; ++j)
          Cv[(size_t)(row0 + j) * N + col] = (__bf16)acc[m][n][j];
      }
    }
}

// ---------------------------------------------------------------------------
// K-only RoPE/RMS (blocks [0,4096), heads 16..19) + V transpose (blocks
// [4096,6144), f32 mode only). Q rope is fused into attn's Q load.
// ---------------------------------------------------------------------------
__global__ __launch_bounds__(256) void rope_vtrans(__bf16* __restrict__ qkv,
                                                   const float* __restrict__ csF,
                                                   __bf16* __restrict__ vt,
                                                   const void* __restrict__ cosRaw) {
  const int blk = blockIdx.x, tid = threadIdx.x;
  if (blk < 4096) {                         // K RoPE + RMS (heads 16..19)
    const int gw = blk * 4 + (tid >> 6);    // 0..16383
    const int lane = tid & 63;
    const int head = 16 + (gw & 3);
    const int m = gw >> 2;                  // 0..4095
    const int t = m & 2047;
    __bf16* p = qkv + (size_t)m * 3072 + head * 128;
    const float x1 = (float)p[lane];
    const float x2 = (float)p[lane + 64];
    const float c = csF[t * 64 + lane];
    const float s = csF[131072 + t * 64 + lane];
    const float y1 = x1 * c + x2 * s;
    const float y2 = x2 * c - x1 * s;
    float ss = y1 * y1 + y2 * y2;
    #pragma unroll
    for (int mk = 32; mk >= 1; mk >>= 1) ss += __shfl_xor(ss, mk, 64);
    const float inv = rsqrtf(ss * (1.0f / 128.0f) + 1.1920929e-7f);
    p[lane] = (__bf16)(y1 * inv);
    p[lane + 64] = (__bf16)(y2 * inv);
    return;
  }
  if (is_bf16_mode(cosRaw)) return;         // bf16 mode: VT already written
  // V transpose (f32 mode): vb in [0,2048) = z(2) x y(16) x x(64)
  __shared__ __bf16 t[32][33];
  const int vb = blk - 4096;
  const int z = vb >> 10, rem = vb & 1023;
  const int x = rem & 63, y = rem >> 6;
  const int tx = tid & 31, ty = tid >> 5;
  const int t0 = x * 32, c0 = y * 32;
  #pragma unroll
  for (int i = 0; i < 32; i += 8)
    t[ty + i][tx] = qkv[(size_t)(z * 2048 + t0 + ty + i) * 3072 + 2560 + c0 + tx];
  __syncthreads();
  #pragma unroll
  for (int i = 0; i < 32; i += 8)
    vt[(size_t)(z * 512 + c0 + ty + i) * 2048 + t0 + tx] = t[tx][ty + i];
}

// ---------------------------------------------------------------------------
// GQA causal flash attention v8: 512 threads / 8 waves, TWO q-heads per block
// sharing one K/V staging stream (GQA heads of the same kvh re-read identical
// K/V — staging traffic and per-tile vmcnt stalls halve). Waves 0-3 -> head
// h2*2+0, waves 4-7 -> head h2*2+1; same qt for both groups so the verified
// two-phase masked loop is byte-identical per group. LDS 48KB (Kl+Vl+Pl[8]).
// Grid 512 = 8 grp x (2 h2 x 32 qt), heaviest qt first.
// ---------------------------------------------------------------------------
__global__ __launch_bounds__(512) void attn_fwd8(const __bf16* __restrict__ qkv,
                                                 const __bf16* __restrict__ vt,
                                                 __bf16* __restrict__ out,
                                                 const float* __restrict__ csF,
                                                 const void* __restrict__ cosRawT,
                                                 const void* __restrict__ sinRawT) {
  __shared__ __attribute__((aligned(16))) __bf16 Kl[64 * 128];
  __shared__ __attribute__((aligned(16))) __bf16 Vl[128 * 64];
  __shared__ __attribute__((aligned(16))) __bf16 Pl[8][16][64];

  const int tid = threadIdx.x, lane = tid & 63, w = tid >> 6;   // w 0..7
  const int wl = w & 3;                        // wave within head-group
  const int r = lane & 15, g = lane >> 4;
  const int lid = blockIdx.x;
  const int grp = lid & 7, inner = lid >> 3;   // inner 0..63
  const int b = grp >> 2, kvh = grp & 3;
  const int h2 = inner & 1;
  const int qt = 31 - (inner >> 1);            // heaviest first (verified best)
  const int h = kvh * 4 + h2 * 2 + (w >> 2);   // this wave's head
  const int qpos = qt * 64 + wl * 16 + r;      // loop-invariant
  const __bf16* Kbase = qkv + (size_t)(b * 2048) * 3072 + 2048 + kvh * 128;
  const __bf16* Vbase = vt + (size_t)((b * 4 + kvh) * 128) * 2048;

// 512 threads x 2 iters x 16B = 16KB per buffer; swizzle formulas depend only
// on o_ (byte offset), identical to the verified 256-thread/4-iter version.
#define STAGE(kt)                                                               \
  {                                                                             \
    _Pragma("unroll")                                                           \
    for (int i_ = 0; i_ < 2; ++i_) {                                            \
      const int o_ = tid * 16 + i_ * 8192;                                      \
      const int krow_ = o_ >> 8;                                                \
      const int jj_ = (o_ >> 4) & 15;                                           \
      const int gj_ = (jj_ & 8) | ((jj_ ^ krow_) & 7);                          \
      gload_lds16(Kbase + (size_t)((kt) * 64 + krow_) * 3072 + gj_ * 8,         \
                  (char*)Kl + o_);                                              \
      const int d_ = o_ >> 7;                                                   \
      const int j2_ = (o_ >> 4) & 7;                                            \
      const int g2_ = j2_ ^ (d_ & 7);                                           \
      gload_lds16(Vbase + (size_t)d_ * 2048 + (kt) * 64 + g2_ * 8,              \
                  (char*)Vl + o_);                                              \
    }                                                                           \
  }

#define ATTN_TILE(kt, MASKED)                                                   \
  {                                                                             \
    STAGE(kt);                                                                  \
    asm volatile("s_waitcnt vmcnt(0)" ::: "memory");                            \
    __syncthreads();                                                            \
    f32x4 sacc[4] = {};                                                         \
    _Pragma("unroll")                                                           \
    for (int kb = 0; kb < 4; ++kb) {                                            \
      const int jj = kb * 4 + g;                                                \
      const int jp = (jj & 8) | ((jj ^ (r & 7)) & 7);                           \
      _Pragma("unroll")                                                         \
      for (int n = 0; n < 4; ++n) {                                             \
        const bf16_8 kf = *reinterpret_cast<const bf16_8*>(                     \
            (char*)Kl + (n * 16 + r) * 256 + jp * 16);                          \
        sacc[n] = __builtin_amdgcn_mfma_f32_16x16x32_bf16(kf, qf[kb], sacc[n], 0, 0, 0); \
      }                                                                         \
    }                                                                           \
    float p[4][4];                                                              \
    float pm = -1e30f;                                                          \
    _Pragma("unroll")                                                           \
    for (int n = 0; n < 4; ++n)                                                 \
      _Pragma("unroll")                                                         \
      for (int j = 0; j < 4; ++j) {                                             \
        float sv = sacc[n][j];                                                  \
        if (MASKED && ((kt) * 64 + n * 16 + g * 4 + j > qpos)) sv = -1e30f;     \
        p[n][j] = sv;                                                           \
        pm = fmaxf(pm, sv);                                                     \
      }                                                                         \
    pm = fmaxf(pm, __shfl_xor(pm, 16, 64));                                     \
    pm = fmaxf(pm, __shfl_xor(pm, 32, 64));                                     \
    float mn = mst;                                                             \
    if (!__all(pm - mst <= 12.0f)) {                                            \
      mn = fmaxf(mst, pm);                                                      \
      const float alpha = exp2f(mst - mn);                                      \
      mst = mn;                                                                 \
      lst *= alpha;                                                             \
      float av[4];                                                              \
      _Pragma("unroll")                                                         \
      for (int j = 0; j < 4; ++j) av[j] = __shfl(alpha, g * 4 + j, 64);         \
      _Pragma("unroll")                                                         \
      for (int dt = 0; dt < 8; ++dt)                                            \
        _Pragma("unroll")                                                       \
        for (int j = 0; j < 4; ++j) accO[dt][j] *= av[j];                       \
    }                                                                           \
    float rs = 0.0f;                                                            \
    _Pragma("unroll")                                                           \
    for (int n = 0; n < 4; ++n)                                                 \
      _Pragma("unroll")                                                         \
      for (int j = 0; j < 4; ++j) {                                             \
        p[n][j] = exp2f(p[n][j] - mn);                                          \
        rs += p[n][j];                                                          \
      }                                                                         \
    rs += __shfl_xor(rs, 16, 64);                                               \
    rs += __shfl_xor(rs, 32, 64);                                               \
    lst += rs;                                                                  \
    _Pragma("unroll")                                                           \
    for (int n = 0; n < 4; ++n) {                                               \
      bf16_4 pk;                                                                \
      _Pragma("unroll")                                                         \
      for (int j = 0; j < 4; ++j) pk[j] = (__bf16)p[n][j];                      \
      const int blk = 2 * n + (g >> 1);                                         \
      char* pw = plw + r * 128 + ((blk ^ (r & 7)) << 4) + (g & 1) * 8;          \
      *reinterpret_cast<bf16_4*>(pw) = pk;                                      \
    }                                                                           \
    _Pragma("unroll")                                                           \
    for (int half = 0; half < 2; ++half) {                                      \
      const bf16_8 pa = *reinterpret_cast<const bf16_8*>(                       \
          plw + r * 128 + (((half * 4 + g) ^ (r & 7)) << 4));                   \
      _Pragma("unroll")                                                         \
      for (int dt = 0; dt < 8; ++dt) {                                          \
        const int d = dt * 16 + r;                                              \
        const bf16_8 vf = *reinterpret_cast<const bf16_8*>(                     \
            (char*)Vl + d * 128 + ((half * 4 + g) ^ (d & 7)) * 16);             \
        accO[dt] = __builtin_amdgcn_mfma_f32_16x16x32_bf16(pa, vf, accO[dt], 0, 0, 0); \
      }                                                                         \
    }                                                                           \
    __syncthreads();                                                            \
  }

  // --- Q fragments: raw load + fused RoPE + RMS + pre-scale ---
  bf16_8 qf[4];
  {
    const int trow = qt * 64 + wl * 16 + r;    // position within batch
    const __bf16* qp = qkv + (size_t)(b * 2048 + trow) * 3072 + h * 128 + g * 8;
    bf16_8 rq[4];
    #pragma unroll
    for (int kb = 0; kb < 4; ++kb) rq[kb] = *reinterpret_cast<const bf16_8*>(qp + kb * 32);
    // rope tables: vectorized loads (bf16_8 in bf16 mode, float4 pairs in f32).
    float cv[16], sv[16];
    if (is_bf16_mode(cosRawT)) {
      const __bf16* cb = reinterpret_cast<const __bf16*>(cosRawT) + (size_t)trow * 64 + g * 8;
      const __bf16* sb = reinterpret_cast<const __bf16*>(sinRawT) + (size_t)trow * 64 + g * 8;
      const bf16_8 clo = *reinterpret_cast<const bf16_8*>(cb);
      const bf16_8 chi = *reinterpret_cast<const bf16_8*>(cb + 32);
      const bf16_8 slo = *reinterpret_cast<const bf16_8*>(sb);
      const bf16_8 shi = *reinterpret_cast<const bf16_8*>(sb + 32);
      #pragma unroll
      for (int i = 0; i < 8; ++i) {
        cv[i] = (float)clo[i];  cv[8 + i] = (float)chi[i];
        sv[i] = (float)slo[i];  sv[8 + i] = (float)shi[i];
      }
    } else {
      const float* cb = csF + (size_t)trow * 64 + g * 8;
      const float* sb = csF + 131072 + (size_t)trow * 64 + g * 8;
      #pragma unroll
      for (int i = 0; i < 2; ++i) {
        const float4 c0 = *reinterpret_cast<const float4*>(cb + i * 4);
        const float4 c1 = *reinterpret_cast<const float4*>(cb + 32 + i * 4);
        const float4 s0 = *reinterpret_cast<const float4*>(sb + i * 4);
        const float4 s1 = *reinterpret_cast<const float4*>(sb + 32 + i * 4);
        cv[i * 4 + 0] = c0.x; cv[i * 4 + 1] = c0.y; cv[i * 4 + 2] = c0.z; cv[i * 4 + 3] = c0.w;
        cv[8 + i * 4 + 0] = c1.x; cv[8 + i * 4 + 1] = c1.y; cv[8 + i * 4 + 2] = c1.z; cv[8 + i * 4 + 3] = c1.w;
        sv[i * 4 + 0] = s0.x; sv[i * 4 + 1] = s0.y; sv[i * 4 + 2] = s0.z; sv[i * 4 + 3] = s0.w;
        sv[8 + i * 4 + 0] = s1.x; sv[8 + i * 4 + 1] = s1.y; sv[8 + i * 4 + 2] = s1.z; sv[8 + i * 4 + 3] = s1.w;
      }
    }
    float y[4][8];
    float ss = 0.0f;
    #pragma unroll
    for (int i = 0; i < 8; ++i) {
      const float c0 = cv[i],     s0 = sv[i];        // d in [0,32)+g8
      const float c1 = cv[8 + i], s1 = sv[8 + i];    // d in [32,64)+g8
      const float xa0 = (float)rq[0][i], xb0 = (float)rq[2][i];   // pair (d, d+64)
      const float xa1 = (float)rq[1][i], xb1 = (float)rq[3][i];
      y[0][i] = xa0 * c0 + xb0 * s0;
      y[2][i] = xb0 * c0 - xa0 * s0;
      y[1][i] = xa1 * c1 + xb1 * s1;
      y[3][i] = xb1 * c1 - xa1 * s1;
      ss += y[0][i] * y[0][i] + y[1][i] * y[1][i] + y[2][i] * y[2][i] + y[3][i] * y[3][i];
    }
    ss += __shfl_xor(ss, 16, 64);
    ss += __shfl_xor(ss, 32, 64);
    const float inv = rsqrtf(ss * (1.0f / 128.0f) + 1.1920929e-7f) * 0.12751743f;
    #pragma unroll
    for (int kb = 0; kb < 4; ++kb)
      #pragma unroll
      for (int i = 0; i < 8; ++i) qf[kb][i] = (__bf16)(y[kb][i] * inv);
  }

  char* const plw = (char*)Pl + w * 2048;
  f32x4 accO[8] = {};
  float mst = -1e30f, lst = 0.0f;

  // Tiles 0..qt-1: strictly below the diagonal, no mask needed.
  for (int kt = 0; kt < qt; ++kt) ATTN_TILE(kt, false);
  // Tile qt: diagonal, masked (qt = 0 degenerates to this alone).
  ATTN_TILE(qt, true);

  // --- epilogue: normalize + store ---
  float lv[4];
  #pragma unroll
  for (int j = 0; j < 4; ++j) lv[j] = 1.0f / __shfl(lst, g * 4 + j, 64);
  #pragma unroll
  for (int dt = 0; dt < 8; ++dt)
    #pragma unroll
    for (int j = 0; j < 4; ++j) {
      const int t = qt * 64 + wl * 16 + g * 4 + j;
      out[(size_t)(b * 2048 + t) * 2048 + h * 128 + dt * 16 + r] = (__bf16)(accO[dt][j] * lv[j]);
    }
#undef ATTN_TILE
#undef STAGE
}

// ---------------------------------------------------------------------------
extern "C" void kernel_launch(void* const* d_in, const int* in_sizes, int n_in,
                              void* d_out, int out_size, void* d_ws, size_t ws_size,
                              hipStream_t stream) {
  const void* x    = d_in[0];
  const void* cosT = d_in[1];
  const void* sinT = d_in[2];
  const void* W_Q  = d_in[3];
  const void* W_K  = d_in[4];
  const void* W_V  = d_in[5];
  const void* W_O  = d_in[6];

  const int B = 2, T = 2048, C = 2048;
  const int M = B * T;        // 4096
  const int NQKV = 3072;

  char* ws = (char*)d_ws;
  ws += 256;                                     // (reserved, keeps prior layout)
  float*  csF  = (float*)ws;                     ws += (size_t)2 * 131072 * 4;   // 1 MB
  __bf16* xb   = (__bf16*)ws;                    ws += (size_t)M * C * 2;        // 16.8 MB
  __bf16* Wt   = (__bf16*)ws;                    ws += (size_t)NQKV * C * 2;     // 12.6 MB
  __bf16* WOt  = (__bf16*)ws;                    ws += (size_t)C * C * 2;        // 8.4 MB
  __bf16* QKV  = (__bf16*)ws;                    ws += (size_t)M * NQKV * 2;     // 25.2 MB
  __bf16* AO   = (__bf16*)ws;                    ws += (size_t)M * C * 2;        // 16.8 MB
  __bf16* VT   = xb;                             // [2][4][128][2048] = 4 MB, reuses xb

  prep_all<<<dim3(9728), 256, 0, stream>>>(cosT, sinT, x, W_Q, W_K, W_V, W_O,
                                           csF, xb, Wt, WOt);
  gemm8p3<<<dim3((M / 128) * (NQKV / 384)), 512, 0, stream>>>(xb, x, Wt, QKV, VT, M, NQKV, C, cosT);
  rope_vtrans<<<dim3(6144), 256, 0, stream>>>(QKV, csF, VT, cosT);
  attn_fwd8<<<dim3(512), 512, 0, stream>>>(QKV, VT, AO, csF, cosT, sinT);
  gemm8p<<<dim3((M / 128) * (C / 256)), 512, 0, stream>>>(AO, WOt, d_out, M, C, C, cosT);
}

// Round 32
// 194.203 us; speedup vs baseline: 1.0561x; 1.0561x over previous
//
#include <hip/hip_runtime.h>
#include <hip/hip_bf16.h>
#include <stdint.h>

typedef __bf16 bf16_4 __attribute__((ext_vector_type(4)));
typedef __bf16 bf16_8 __attribute__((ext_vector_type(8)));
typedef float f32x4 __attribute__((ext_vector_type(4)));

#define AS1 __attribute__((address_space(1)))
#define AS3 __attribute__((address_space(3)))

__device__ __forceinline__ void gload_lds16(const void* g, void* l) {
  __builtin_amdgcn_global_load_lds((const AS1 void*)g, (AS3 void*)l, 16, 0, 0);
}

// isb: device-side dtype probe. cos[0] == 1.0 exactly; f32 1.0 low halfword =
// 0x0000, packed bf16 (1.0,1.0) = 0x3F803F80 -> low halfword 0x3F80.
__device__ __forceinline__ bool is_bf16_mode(const void* cosT) {
  return ((*reinterpret_cast<const uint32_t*>(cosT)) & 0xFFFFu) == 0x3F80u;
}

// ---------------------------------------------------------------------------
// Fused prep: [0,512) cos/sin->f32; [512,4608) x->bf16 (f32 mode ONLY — in
// bf16 mode gemm1 reads x directly); [4608,9728) weight transpose+convert,
// VECTORIZED: 64x32 tiles, one 16B load + one 16B store per thread.
// ---------------------------------------------------------------------------
__global__ __launch_bounds__(256) void prep_all(const void* __restrict__ cosT,
                                                const void* __restrict__ sinT,
                                                const void* __restrict__ x,
                                                const void* __restrict__ WQ,
                                                const void* __restrict__ WK,
                                                const void* __restrict__ WV,
                                                const void* __restrict__ WO,
                                                float* __restrict__ csF,
                                                __bf16* __restrict__ xb,
                                                __bf16* __restrict__ Wt,
                                                __bf16* __restrict__ WOt) {
  const int blk = blockIdx.x, tid = threadIdx.x;
  const bool isb = is_bf16_mode(cosT);
  if (blk < 512) {                      // tables -> f32
    const int i = blk * 256 + tid;
    if (isb) {
      csF[i]          = (float)reinterpret_cast<const __bf16*>(cosT)[i];
      csF[131072 + i] = (float)reinterpret_cast<const __bf16*>(sinT)[i];
    } else {
      csF[i]          = reinterpret_cast<const float*>(cosT)[i];
      csF[131072 + i] = reinterpret_cast<const float*>(sinT)[i];
    }
    return;
  }
  if (blk < 4608) {                     // x -> bf16 (f32 mode only)
    if (isb) return;                    // bf16 mode: gemm reads x directly
    const int i = (blk - 512) * 256 + tid;
    const float4* s = reinterpret_cast<const float4*>(x);
    const float4 a = s[2 * i], c = s[2 * i + 1];
    __bf16 o[8] = {(__bf16)a.x, (__bf16)a.y, (__bf16)a.z, (__bf16)a.w,
                   (__bf16)c.x, (__bf16)c.y, (__bf16)c.z, (__bf16)c.w};
    reinterpret_cast<int4*>(xb)[i] = *reinterpret_cast<int4*>(o);
    return;
  }
  // weight transpose: tb in [0,5120) = (bx 0..159) x (by 0..31), 64x32 tile
  __shared__ __bf16 t[64][33];          // +1 pad: column reads stride 33 = CF
  const int tb = blk - 4608;
  const int bx = tb % 160, by = tb / 160;
  const void* src;
  __bf16* dst;
  int C, c0;
  if (bx < 64)      { src = WQ; dst = Wt;                        C = 2048; c0 = bx * 32; }
  else if (bx < 80) { src = WK; dst = Wt + (size_t)2048 * 2048;  C = 512;  c0 = (bx - 64) * 32; }
  else if (bx < 96) { src = WV; dst = Wt + (size_t)2560 * 2048;  C = 512;  c0 = (bx - 80) * 32; }
  else              { src = WO; dst = WOt;                       C = 2048; c0 = (bx - 96) * 32; }
  const int r0 = by * 64;
  // load: thread -> (row = tid>>2, colblk = (tid&3)*8), one 16B (bf16) or
  // 2x16B (f32) vector load, 8 LDS scalar writes
  {
    const int row = tid >> 2, cb = (tid & 3) * 8;
    bf16_8 v;
    if (isb) {
      v = *reinterpret_cast<const bf16_8*>(
          reinterpret_cast<const __bf16*>(src) + (size_t)(r0 + row) * C + c0 + cb);
    } else {
      const float* sp = reinterpret_cast<const float*>(src) + (size_t)(r0 + row) * C + c0 + cb;
      const float4 a = *reinterpret_cast<const float4*>(sp);
      const float4 b2 = *reinterpret_cast<const float4*>(sp + 4);
      v[0] = (__bf16)a.x;  v[1] = (__bf16)a.y;  v[2] = (__bf16)a.z;  v[3] = (__bf16)a.w;
      v[4] = (__bf16)b2.x; v[5] = (__bf16)b2.y; v[6] = (__bf16)b2.z; v[7] = (__bf16)b2.w;
    }
    #pragma unroll
    for (int k = 0; k < 8; ++k) t[row][cb + k] = v[k];
  }
  __syncthreads();
  // store: thread -> (out col j = tid>>3, row seg = (tid&7)*8), 8 LDS column
  // reads (stride 33, conflict-free) -> one 16B vector store
  {
    const int j = tid >> 3, seg = (tid & 7) * 8;
    bf16_8 v;
    #pragma unroll
    for (int k = 0; k < 8; ++k) v[k] = t[seg + k][j];
    *reinterpret_cast<bf16_8*>(dst + (size_t)(c0 + j) * 2048 + r0 + seg) = v;
  }
}

// ---------------------------------------------------------------------------
// GEMM A: 128x256 tile, BK=64, 8 waves, dbuf LDS (96KB), XOR-swizzle,
// 2 phases/K-tile, counted vmcnt + setprio. 1-D grid, bijective XCD swizzle.
// Output dtype per is_bf16_mode(cosRaw). Used for gemm2 (N=2048, grid 256).
// ---------------------------------------------------------------------------
__global__ __launch_bounds__(512) void gemm8p(const __bf16* __restrict__ A,
                                              const __bf16* __restrict__ Bt,
                                              void* __restrict__ Cv,
                                              int M, int N, int K,
                                              const void* __restrict__ cosRaw) {
  __shared__ __attribute__((aligned(16))) __bf16 As[2][128 * 64];
  __shared__ __attribute__((aligned(16))) __bf16 Bs[2][256 * 64];
  const int tid = threadIdx.x;
  const int lane = tid & 63, w = tid >> 6;
  const int wm = w >> 2, wn = w & 3;
  const int r = lane & 15, g = lane >> 4;
  const int q8 = gridDim.x >> 3;
  const int wg = (blockIdx.x & 7) * q8 + (blockIdx.x >> 3);
  const int gx = M >> 7;
  const int bm = (wg % gx) * 128, bn = (wg / gx) * 256;
  const bool isb = is_bf16_mode(cosRaw);
  const int NT = K >> 6;

  f32x4 acc[4][4] = {};

#define STA(kt, p, j)                                                              \
  {                                                                                \
    const int o_ = tid * 16 + (j) * 8192;                                          \
    const int row_ = o_ >> 7, blk_ = (o_ >> 4) & 7;                                \
    gload_lds16(A + (size_t)(bm + row_) * K + (kt) * 64 + ((blk_ ^ (row_ & 7)) << 3), \
                (char*)As[p] + o_);                                                \
  }
#define STB(kt, p, j)                                                              \
  {                                                                                \
    const int o_ = tid * 16 + (j) * 8192;                                          \
    const int rl_ = o_ >> 7, blk_ = (o_ >> 4) & 7;                                 \
    const int gr_ = ((rl_ >> 5) & 3) * 64 + ((rl_ >> 7) & 1) * 32 + (rl_ & 31);    \
    gload_lds16(Bt + (size_t)(bn + gr_) * K + (kt) * 64 + ((blk_ ^ (rl_ & 7)) << 3), \
                (char*)Bs[p] + o_);                                                \
  }

  STA(0, 0, 0); STA(0, 0, 1);
  STB(0, 0, 0); STB(0, 0, 1); STB(0, 0, 2); STB(0, 0, 3);
  asm volatile("s_waitcnt vmcnt(2)\ns_barrier" ::: "memory");

  for (int kt = 0; kt < NT; ++kt) {
    const int cur = kt & 1, nxt = cur ^ 1;
    const bool pf = (kt + 1 < NT);
    const char* Ac = (const char*)As[cur];
    const char* Bc = (const char*)Bs[cur];

    bf16_8 af[4][2], bf[2][2];
    #pragma unroll
    for (int m = 0; m < 4; ++m)
      #pragma unroll
      for (int kk = 0; kk < 2; ++kk) {
        const int row = wm * 64 + m * 16 + r;
        af[m][kk] = *reinterpret_cast<const bf16_8*>(
            Ac + row * 128 + (((kk * 4 + g) ^ (row & 7)) << 4));
      }
    #pragma unroll
    for (int n = 0; n < 2; ++n)
      #pragma unroll
      for (int kk = 0; kk < 2; ++kk) {
        const int rl = wn * 32 + n * 16 + r;
        bf[n][kk] = *reinterpret_cast<const bf16_8*>(
            Bc + rl * 128 + (((kk * 4 + g) ^ (rl & 7)) << 4));
      }
    if (pf) { STA(kt + 1, nxt, 0); STA(kt + 1, nxt, 1); STB(kt + 1, nxt, 0); }
    __builtin_amdgcn_s_barrier();
    __builtin_amdgcn_s_setprio(1);
    #pragma unroll
    for (int kk = 0; kk < 2; ++kk)
      #pragma unroll
      for (int m = 0; m < 4; ++m)
        #pragma unroll
        for (int n = 0; n < 2; ++n)
          acc[m][n] = __builtin_amdgcn_mfma_f32_16x16x32_bf16(af[m][kk], bf[n][kk], acc[m][n], 0, 0, 0);
    __builtin_amdgcn_s_setprio(0);
    if (pf) asm volatile("s_waitcnt vmcnt(3)\ns_barrier" ::: "memory");
    else    asm volatile("s_waitcnt vmcnt(0)\ns_barrier" ::: "memory");

    bf16_8 bg[2][2];
    #pragma unroll
    for (int n = 0; n < 2; ++n)
      #pragma unroll
      for (int kk = 0; kk < 2; ++kk) {
        const int rl = 128 + wn * 32 + n * 16 + r;
        bg[n][kk] = *reinterpret_cast<const bf16_8*>(
            Bc + rl * 128 + (((kk * 4 + g) ^ (rl & 7)) << 4));
      }
    if (pf) { STB(kt + 1, nxt, 1); STB(kt + 1, nxt, 2); STB(kt + 1, nxt, 3); }
    __builtin_amdgcn_s_barrier();
    __builtin_amdgcn_s_setprio(1);
    #pragma unroll
    for (int kk = 0; kk < 2; ++kk)
      #pragma unroll
      for (int m = 0; m < 4; ++m)
        #pragma unroll
        for (int n = 0; n < 2; ++n)
          acc[m][n + 2] = __builtin_amdgcn_mfma_f32_16x16x32_bf16(af[m][kk], bg[n][kk], acc[m][n + 2], 0, 0, 0);
    __builtin_amdgcn_s_setprio(0);
    if (pf) asm volatile("s_waitcnt vmcnt(2)\ns_barrier" ::: "memory");
    else    asm volatile("s_waitcnt vmcnt(0)\ns_barrier" ::: "memory");
  }
#undef STA
#undef STB

  #pragma unroll
  for (int m = 0; m < 4; ++m)
    #pragma unroll
    for (int n = 0; n < 4; ++n)
      #pragma unroll
      for (int j = 0; j < 4; ++j) {
        const int row = bm + wm * 64 + m * 16 + g * 4 + j;
        const int col = bn + wn * 64 + n * 16 + r;
        const float v = acc[m][n][j];
        if (isb) reinterpret_cast<__bf16*>(Cv)[(size_t)row * N + col] = (__bf16)v;
        else     reinterpret_cast<float*>(Cv)[(size_t)row * N + col] = v;
      }
}

// ---------------------------------------------------------------------------
// GEMM B: 128x384 tile for N=3072 -> grid 256 = 1 block/CU exactly.
// 3 phases/K-tile, counted-vmcnt ledger. A operand: bf16 mode reads x
// directly (Araw). V outputs (col >= 2560, bf16 mode) go directly to VT
// in transposed layout (packed 8B store); f32 mode keeps the old path.
// ---------------------------------------------------------------------------
__global__ __launch_bounds__(512) void gemm8p3(const __bf16* __restrict__ Acvt,
                                               const void* __restrict__ Araw,
                                               const __bf16* __restrict__ Bt,
                                               __bf16* __restrict__ Cv,
                                               __bf16* __restrict__ vtOut,
                                               int M, int N, int K,
                                               const void* __restrict__ cosRaw) {
  __shared__ __attribute__((aligned(16))) __bf16 As[2][128 * 64];
  __shared__ __attribute__((aligned(16))) __bf16 Bs[2][384 * 64];
  const int tid = threadIdx.x;
  const int lane = tid & 63, w = tid >> 6;
  const int wm = w >> 2, wn = w & 3;
  const int r = lane & 15, g = lane >> 4;
  const int q8 = gridDim.x >> 3;
  const int wg = (blockIdx.x & 7) * q8 + (blockIdx.x >> 3);
  const int gx = M >> 7;
  const int bm = (wg % gx) * 128, bn = (wg / gx) * 384;
  const int NT = K >> 6;
  const bool isb = is_bf16_mode(cosRaw);
  const __bf16* A = isb ? (const __bf16*)Araw : Acvt;

  f32x4 acc[4][6] = {};

#define STA3(kt, p, j)                                                             \
  {                                                                                \
    const int o_ = tid * 16 + (j) * 8192;                                          \
    const int row_ = o_ >> 7, blk_ = (o_ >> 4) & 7;                                \
    gload_lds16(A + (size_t)(bm + row_) * K + (kt) * 64 + ((blk_ ^ (row_ & 7)) << 3), \
                (char*)As[p] + o_);                                                \
  }
#define STB3(kt, p, j)                                                             \
  {                                                                                \
    const int o_ = tid * 16 + (j) * 8192;                                          \
    const int rl_ = o_ >> 7, blk_ = (o_ >> 4) & 7;                                 \
    const int gr_ = ((rl_ & 127) >> 5) * 96 + (rl_ >> 7) * 32 + (rl_ & 31);        \
    gload_lds16(Bt + (size_t)(bn + gr_) * K + (kt) * 64 + ((blk_ ^ (rl_ & 7)) << 3), \
                (char*)Bs[p] + o_);                                                \
  }

  STA3(0, 0, 0); STA3(0, 0, 1);
  STB3(0, 0, 0); STB3(0, 0, 1); STB3(0, 0, 2);
  STB3(0, 0, 3); STB3(0, 0, 4); STB3(0, 0, 5);
  asm volatile("s_waitcnt vmcnt(4)\ns_barrier" ::: "memory");

  for (int kt = 0; kt < NT; ++kt) {
    const int cur = kt & 1, nxt = cur ^ 1;
    const bool pf = (kt + 1 < NT);
    const char* Ac = (const char*)As[cur];
    const char* Bc = (const char*)Bs[cur];
    bf16_8 af[4][2];

    // ---- phase A: all A-frags + B seg0 (n = 0,1) ----
    {
      #pragma unroll
      for (int m = 0; m < 4; ++m)
        #pragma unroll
        for (int kk = 0; kk < 2; ++kk) {
          const int row = wm * 64 + m * 16 + r;
          af[m][kk] = *reinterpret_cast<const bf16_8*>(
              Ac + row * 128 + (((kk * 4 + g) ^ (row & 7)) << 4));
        }
      bf16_8 bf[2][2];
      #pragma unroll
      for (int n = 0; n < 2; ++n)
        #pragma unroll
        for (int kk = 0; kk < 2; ++kk) {
          const int rl = wn * 32 + n * 16 + r;
          bf[n][kk] = *reinterpret_cast<const bf16_8*>(
              Bc + rl * 128 + (((kk * 4 + g) ^ (r & 7)) << 4));
        }
      if (pf) { STA3(kt + 1, nxt, 0); STA3(kt + 1, nxt, 1); STB3(kt + 1, nxt, 0); }
      __builtin_amdgcn_s_barrier();
      __builtin_amdgcn_s_setprio(1);
      #pragma unroll
      for (int kk = 0; kk < 2; ++kk)
        #pragma unroll
        for (int m = 0; m < 4; ++m)
          #pragma unroll
          for (int n = 0; n < 2; ++n)
            acc[m][n] = __builtin_amdgcn_mfma_f32_16x16x32_bf16(af[m][kk], bf[n][kk], acc[m][n], 0, 0, 0);
      __builtin_amdgcn_s_setprio(0);
      if (pf) asm volatile("s_waitcnt vmcnt(5)\ns_barrier" ::: "memory");
      else    asm volatile("s_waitcnt vmcnt(0)\ns_barrier" ::: "memory");
    }

    // ---- phase B: B seg1 (n = 2,3) ----
    {
      bf16_8 bf[2][2];
      #pragma unroll
      for (int n = 0; n < 2; ++n)
        #pragma unroll
        for (int kk = 0; kk < 2; ++kk) {
          const int rl = 128 + wn * 32 + n * 16 + r;
          bf[n][kk] = *reinterpret_cast<const bf16_8*>(
              Bc + rl * 128 + (((kk * 4 + g) ^ (r & 7)) << 4));
        }
      if (pf) { STB3(kt + 1, nxt, 1); STB3(kt + 1, nxt, 2); }
      __builtin_amdgcn_s_barrier();
      __builtin_amdgcn_s_setprio(1);
      #pragma unroll
      for (int kk = 0; kk < 2; ++kk)
        #pragma unroll
        for (int m = 0; m < 4; ++m)
          #pragma unroll
          for (int n = 0; n < 2; ++n)
            acc[m][n + 2] = __builtin_amdgcn_mfma_f32_16x16x32_bf16(af[m][kk], bf[n][kk], acc[m][n + 2], 0, 0, 0);
      __builtin_amdgcn_s_setprio(0);
      if (pf) asm volatile("s_waitcnt vmcnt(5)\ns_barrier" ::: "memory");
      else    asm volatile("s_waitcnt vmcnt(0)\ns_barrier" ::: "memory");
    }

    // ---- phase C: B seg2 (n = 4,5) ----
    {
      bf16_8 bf[2][2];
      #pragma unroll
      for (int n = 0; n < 2; ++n)
        #pragma unroll
        for (int kk = 0; kk < 2; ++kk) {
          const int rl = 256 + wn * 32 + n * 16 + r;
          bf[n][kk] = *reinterpret_cast<const bf16_8*>(
              Bc + rl * 128 + (((kk * 4 + g) ^ (r & 7)) << 4));
        }
      if (pf) { STB3(kt + 1, nxt, 3); STB3(kt + 1, nxt, 4); STB3(kt + 1, nxt, 5); }
      __builtin_amdgcn_s_barrier();
      __builtin_amdgcn_s_setprio(1);
      #pragma unroll
      for (int kk = 0; kk < 2; ++kk)
        #pragma unroll
        for (int m = 0; m < 4; ++m)
          #pragma unroll
          for (int n = 0; n < 2; ++n)
            acc[m][n + 4] = __builtin_amdgcn_mfma_f32_16x16x32_bf16(af[m][kk], bf[n][kk], acc[m][n + 4], 0, 0, 0);
      __builtin_amdgcn_s_setprio(0);
      if (pf) asm volatile("s_waitcnt vmcnt(4)\ns_barrier" ::: "memory");
      else    asm volatile("s_waitcnt vmcnt(0)\ns_barrier" ::: "memory");
    }
  }
#undef STA3
#undef STB3

  #pragma unroll
  for (int m = 0; m < 4; ++m)
    #pragma unroll
    for (int n = 0; n < 6; ++n) {
      const int row0 = bm + wm * 64 + m * 16 + g * 4;   // 4-aligned, +j rows
      const int col  = bn + wn * 96 + n * 16 + r;
      if (isb && col >= 2560) {
        // V output -> VT[b][kvh][d][t0..t0+3], one packed 8B store
        const int vcol = col - 2560;                    // 0..511 = kvh*128+d
        const int bb = row0 >> 11;                      // batch index
        const int t0 = row0 & 2047;                     // 4-aligned
        bf16_4 pk;
        #pragma unroll
        for (int j = 0; j < 4; ++j) pk[j] = (__bf16)acc[m][n][j];
        *reinterpret_cast<bf16_4*>(
            &vtOut[((size_t)bb * 512 + vcol) * 2048 + t0]) = pk;
      } else {
        #pragma unroll
        for (int j = 0; j < 4; ++j)
          Cv[(size_t)(row0 + j) * N + col] = (__bf16)acc[m][n][j];
      }
    }
}

// ---------------------------------------------------------------------------
// K-only RoPE/RMS (blocks [0,4096), heads 16..19) + V transpose (blocks
// [4096,6144), f32 mode only). Q rope is fused into attn_fwd7's Q load.
// ---------------------------------------------------------------------------
__global__ __launch_bounds__(256) void rope_vtrans(__bf16* __restrict__ qkv,
                                                   const float* __restrict__ csF,
                                                   __bf16* __restrict__ vt,
                                                   const void* __restrict__ cosRaw) {
  const int blk = blockIdx.x, tid = threadIdx.x;
  if (blk < 4096) {                         // K RoPE + RMS (heads 16..19)
    const int gw = blk * 4 + (tid >> 6);    // 0..16383
    const int lane = tid & 63;
    const int head = 16 + (gw & 3);
    const int m = gw >> 2;                  // 0..4095
    const int t = m & 2047;
    __bf16* p = qkv + (size_t)m * 3072 + head * 128;
    const float x1 = (float)p[lane];
    const float x2 = (float)p[lane + 64];
    const float c = csF[t * 64 + lane];
    const float s = csF[131072 + t * 64 + lane];
    const float y1 = x1 * c + x2 * s;
    const float y2 = x2 * c - x1 * s;
    float ss = y1 * y1 + y2 * y2;
    #pragma unroll
    for (int mk = 32; mk >= 1; mk >>= 1) ss += __shfl_xor(ss, mk, 64);
    const float inv = rsqrtf(ss * (1.0f / 128.0f) + 1.1920929e-7f);
    p[lane] = (__bf16)(y1 * inv);
    p[lane + 64] = (__bf16)(y2 * inv);
    return;
  }
  if (is_bf16_mode(cosRaw)) return;         // bf16 mode: VT already written
  // V transpose (f32 mode): vb in [0,2048) = z(2) x y(16) x x(64)
  __shared__ __bf16 t[32][33];
  const int vb = blk - 4096;
  const int z = vb >> 10, rem = vb & 1023;
  const int x = rem & 63, y = rem >> 6;
  const int tx = tid & 31, ty = tid >> 5;
  const int t0 = x * 32, c0 = y * 32;
  #pragma unroll
  for (int i = 0; i < 32; i += 8)
    t[ty + i][tx] = qkv[(size_t)(z * 2048 + t0 + ty + i) * 3072 + 2560 + c0 + tx];
  __syncthreads();
  #pragma unroll
  for (int i = 0; i < 32; i += 8)
    vt[(size_t)(z * 512 + c0 + ty + i) * 2048 + t0 + tx] = t[tx][ty + i];
}

// ---------------------------------------------------------------------------
// GQA causal flash attention, v7.5 (verified best configuration).
// ---------------------------------------------------------------------------
__global__ __launch_bounds__(256) void attn_fwd7(const __bf16* __restrict__ qkv,
                                                 const __bf16* __restrict__ vt,
                                                 __bf16* __restrict__ out,
                                                 const float* __restrict__ csF,
                                                 const void* __restrict__ cosRawT,
                                                 const void* __restrict__ sinRawT) {
  __shared__ __attribute__((aligned(16))) __bf16 Kl[64 * 128];
  __shared__ __attribute__((aligned(16))) __bf16 Vl[128 * 64];
  __shared__ __attribute__((aligned(16))) __bf16 Pl[4][16][64];

  const int tid = threadIdx.x, lane = tid & 63, w = tid >> 6;
  const int r = lane & 15, g = lane >> 4;
  const int lid = blockIdx.x;
  const int grp = lid & 7, inner = lid >> 3;   // inner 0..127
  const int b = grp >> 2, kvh = grp & 3;
  const int h = kvh * 4 + (inner & 3);
  const int qt = 31 - (inner >> 2);            // heaviest first (verified best)
  const int qpos = qt * 64 + w * 16 + r;       // loop-invariant
  const __bf16* Kbase = qkv + (size_t)(b * 2048) * 3072 + 2048 + kvh * 128;
  const __bf16* Vbase = vt + (size_t)((b * 4 + kvh) * 128) * 2048;

#define STAGE(kt)                                                               \
  {                                                                             \
    _Pragma("unroll")                                                           \
    for (int i_ = 0; i_ < 4; ++i_) {                                            \
      const int o_ = tid * 16 + i_ * 4096;                                      \
      const int krow_ = o_ >> 8;                                                \
      const int jj_ = (o_ >> 4) & 15;                                           \
      const int gj_ = (jj_ & 8) | ((jj_ ^ krow_) & 7);                          \
      gload_lds16(Kbase + (size_t)((kt) * 64 + krow_) * 3072 + gj_ * 8,         \
                  (char*)Kl + o_);                                              \
      const int d_ = o_ >> 7;                                                   \
      const int j2_ = (o_ >> 4) & 7;                                            \
      const int g2_ = j2_ ^ (d_ & 7);                                           \
      gload_lds16(Vbase + (size_t)d_ * 2048 + (kt) * 64 + g2_ * 8,              \
                  (char*)Vl + o_);                                              \
    }                                                                           \
  }

#define ATTN_TILE(kt, MASKED)                                                   \
  {                                                                             \
    STAGE(kt);                                                                  \
    asm volatile("s_waitcnt vmcnt(0)" ::: "memory");                            \
    __syncthreads();                                                            \
    f32x4 sacc[4] = {};                                                         \
    _Pragma("unroll")                                                           \
    for (int kb = 0; kb < 4; ++kb) {                                            \
      const int jj = kb * 4 + g;                                                \
      const int jp = (jj & 8) | ((jj ^ (r & 7)) & 7);                           \
      _Pragma("unroll")                                                         \
      for (int n = 0; n < 4; ++n) {                                             \
        const bf16_8 kf = *reinterpret_cast<const bf16_8*>(                     \
            (char*)Kl + (n * 16 + r) * 256 + jp * 16);                          \
        sacc[n] = __builtin_amdgcn_mfma_f32_16x16x32_bf16(kf, qf[kb], sacc[n], 0, 0, 0); \
      }                                                                         \
    }                                                                           \
    float p[4][4];                                                              \
    float pm = -1e30f;                                                          \
    _Pragma("unroll")                                                           \
    for (int n = 0; n < 4; ++n)                                                 \
      _Pragma("unroll")                                                         \
      for (int j = 0; j < 4; ++j) {                                             \
        float sv = sacc[n][j];                                                  \
        if (MASKED && ((kt) * 64 + n * 16 + g * 4 + j > qpos)) sv = -1e30f;     \
        p[n][j] = sv;                                                           \
        pm = fmaxf(pm, sv);                                                     \
      }                                                                         \
    pm = fmaxf(pm, __shfl_xor(pm, 16, 64));                                     \
    pm = fmaxf(pm, __shfl_xor(pm, 32, 64));                                     \
    float mn = mst;                                                             \
    if (!__all(pm - mst <= 12.0f)) {                                            \
      mn = fmaxf(mst, pm);                                                      \
      const float alpha = exp2f(mst - mn);                                      \
      mst = mn;                                                                 \
      lst *= alpha;                                                             \
      float av[4];                                                              \
      _Pragma("unroll")                                                         \
      for (int j = 0; j < 4; ++j) av[j] = __shfl(alpha, g * 4 + j, 64);         \
      _Pragma("unroll")                                                         \
      for (int dt = 0; dt < 8; ++dt)                                            \
        _Pragma("unroll")                                                       \
        for (int j = 0; j < 4; ++j) accO[dt][j] *= av[j];                       \
    }                                                                           \
    float rs = 0.0f;                                                            \
    _Pragma("unroll")                                                           \
    for (int n = 0; n < 4; ++n)                                                 \
      _Pragma("unroll")                                                         \
      for (int j = 0; j < 4; ++j) {                                             \
        p[n][j] = exp2f(p[n][j] - mn);                                          \
        rs += p[n][j];                                                          \
      }                                                                         \
    rs += __shfl_xor(rs, 16, 64);                                               \
    rs += __shfl_xor(rs, 32, 64);                                               \
    lst += rs;                                                                  \
    _Pragma("unroll")                                                           \
    for (int n = 0; n < 4; ++n) {                                               \
      bf16_4 pk;                                                                \
      _Pragma("unroll")                                                         \
      for (int j = 0; j < 4; ++j) pk[j] = (__bf16)p[n][j];                      \
      const int blk = 2 * n + (g >> 1);                                         \
      char* pw = plw + r * 128 + ((blk ^ (r & 7)) << 4) + (g & 1) * 8;          \
      *reinterpret_cast<bf16_4*>(pw) = pk;                                      \
    }                                                                           \
    _Pragma("unroll")                                                           \
    for (int half = 0; half < 2; ++half) {                                      \
      const bf16_8 pa = *reinterpret_cast<const bf16_8*>(                       \
          plw + r * 128 + (((half * 4 + g) ^ (r & 7)) << 4));                   \
      _Pragma("unroll")                                                         \
      for (int dt = 0; dt < 8; ++dt) {                                          \
        const int d = dt * 16 + r;                                              \
        const bf16_8 vf = *reinterpret_cast<const bf16_8*>(                     \
            (char*)Vl + d * 128 + ((half * 4 + g) ^ (d & 7)) * 16);             \
        accO[dt] = __builtin_amdgcn_mfma_f32_16x16x32_bf16(pa, vf, accO[dt], 0, 0, 0); \
      }                                                                         \
    }                                                                           \
    __syncthreads();                                                            \
  }

  // --- Q fragments: raw load + fused RoPE + RMS + pre-scale ---
  bf16_8 qf[4];
  {
    const int trow = qt * 64 + w * 16 + r;     // position within batch
    const __bf16* qp = qkv + (size_t)(b * 2048 + trow) * 3072 + h * 128 + g * 8;
    bf16_8 rq[4];
    #pragma unroll
    for (int kb = 0; kb < 4; ++kb) rq[kb] = *reinterpret_cast<const bf16_8*>(qp + kb * 32);
    // rope tables: vectorized loads (bf16_8 in bf16 mode, float4 pairs in f32).
    float cv[16], sv[16];
    if (is_bf16_mode(cosRawT)) {
      const __bf16* cb = reinterpret_cast<const __bf16*>(cosRawT) + (size_t)trow * 64 + g * 8;
      const __bf16* sb = reinterpret_cast<const __bf16*>(sinRawT) + (size_t)trow * 64 + g * 8;
      const bf16_8 clo = *reinterpret_cast<const bf16_8*>(cb);
      const bf16_8 chi = *reinterpret_cast<const bf16_8*>(cb + 32);
      const bf16_8 slo = *reinterpret_cast<const bf16_8*>(sb);
      const bf16_8 shi = *reinterpret_cast<const bf16_8*>(sb + 32);
      #pragma unroll
      for (int i = 0; i < 8; ++i) {
        cv[i] = (float)clo[i];  cv[8 + i] = (float)chi[i];
        sv[i] = (float)slo[i];  sv[8 + i] = (float)shi[i];
      }
    } else {
      const float* cb = csF + (size_t)trow * 64 + g * 8;
      const float* sb = csF + 131072 + (size_t)trow * 64 + g * 8;
      #pragma unroll
      for (int i = 0; i < 2; ++i) {
        const float4 c0 = *reinterpret_cast<const float4*>(cb + i * 4);
        const float4 c1 = *reinterpret_cast<const float4*>(cb + 32 + i * 4);
        const float4 s0 = *reinterpret_cast<const float4*>(sb + i * 4);
        const float4 s1 = *reinterpret_cast<const float4*>(sb + 32 + i * 4);
        cv[i * 4 + 0] = c0.x; cv[i * 4 + 1] = c0.y; cv[i * 4 + 2] = c0.z; cv[i * 4 + 3] = c0.w;
        cv[8 + i * 4 + 0] = c1.x; cv[8 + i * 4 + 1] = c1.y; cv[8 + i * 4 + 2] = c1.z; cv[8 + i * 4 + 3] = c1.w;
        sv[i * 4 + 0] = s0.x; sv[i * 4 + 1] = s0.y; sv[i * 4 + 2] = s0.z; sv[i * 4 + 3] = s0.w;
        sv[8 + i * 4 + 0] = s1.x; sv[8 + i * 4 + 1] = s1.y; sv[8 + i * 4 + 2] = s1.z; sv[8 + i * 4 + 3] = s1.w;
      }
    }
    float y[4][8];
    float ss = 0.0f;
    #pragma unroll
    for (int i = 0; i < 8; ++i) {
      const float c0 = cv[i],     s0 = sv[i];        // d in [0,32)+g8
      const float c1 = cv[8 + i], s1 = sv[8 + i];    // d in [32,64)+g8
      const float xa0 = (float)rq[0][i], xb0 = (float)rq[2][i];   // pair (d, d+64)
      const float xa1 = (float)rq[1][i], xb1 = (float)rq[3][i];
      y[0][i] = xa0 * c0 + xb0 * s0;
      y[2][i] = xb0 * c0 - xa0 * s0;
      y[1][i] = xa1 * c1 + xb1 * s1;
      y[3][i] = xb1 * c1 - xa1 * s1;
      ss += y[0][i] * y[0][i] + y[1][i] * y[1][i] + y[2][i] * y[2][i] + y[3][i] * y[3][i];
    }
    ss += __shfl_xor(ss, 16, 64);
    ss += __shfl_xor(ss, 32, 64);
    const float inv = rsqrtf(ss * (1.0f / 128.0f) + 1.1920929e-7f) * 0.12751743f;
    #pragma unroll
    for (int kb = 0; kb < 4; ++kb)
      #pragma unroll
      for (int i = 0; i < 8; ++i) qf[kb][i] = (__bf16)(y[kb][i] * inv);
  }

  char* const plw = (char*)Pl + w * 2048;
  f32x4 accO[8] = {};
  float mst = -1e30f, lst = 0.0f;

  // Tiles 0..qt-1: strictly below the diagonal, no mask needed.
  for (int kt = 0; kt < qt; ++kt) ATTN_TILE(kt, false);
  // Tile qt: diagonal, masked (qt = 0 degenerates to this alone).
  ATTN_TILE(qt, true);

  // --- epilogue: normalize + store ---
  float lv[4];
  #pragma unroll
  for (int j = 0; j < 4; ++j) lv[j] = 1.0f / __shfl(lst, g * 4 + j, 64);
  #pragma unroll
  for (int dt = 0; dt < 8; ++dt)
    #pragma unroll
    for (int j = 0; j < 4; ++j) {
      const int t = qt * 64 + w * 16 + g * 4 + j;
      out[(size_t)(b * 2048 + t) * 2048 + h * 128 + dt * 16 + r] = (__bf16)(accO[dt][j] * lv[j]);
    }
#undef ATTN_TILE
#undef STAGE
}

// ---------------------------------------------------------------------------
extern "C" void kernel_launch(void* const* d_in, const int* in_sizes, int n_in,
                              void* d_out, int out_size, void* d_ws, size_t ws_size,
                              hipStream_t stream) {
  const void* x    = d_in[0];
  const void* cosT = d_in[1];
  const void* sinT = d_in[2];
  const void* W_Q  = d_in[3];
  const void* W_K  = d_in[4];
  const void* W_V  = d_in[5];
  const void* W_O  = d_in[6];

  const int B = 2, T = 2048, C = 2048;
  const int M = B * T;        // 4096
  const int NQKV = 3072;

  char* ws = (char*)d_ws;
  ws += 256;                                     // (reserved, keeps prior layout)
  float*  csF  = (float*)ws;                     ws += (size_t)2 * 131072 * 4;   // 1 MB
  __bf16* xb   = (__bf16*)ws;                    ws += (size_t)M * C * 2;        // 16.8 MB
  __bf16* Wt   = (__bf16*)ws;                    ws += (size_t)NQKV * C * 2;     // 12.6 MB
  __bf16* WOt  = (__bf16*)ws;                    ws += (size_t)C * C * 2;        // 8.4 MB
  __bf16* QKV  = (__bf16*)ws;                    ws += (size_t)M * NQKV * 2;     // 25.2 MB
  __bf16* AO   = (__bf16*)ws;                    ws += (size_t)M * C * 2;        // 16.8 MB
  __bf16* VT   = xb;                             // [2][4][128][2048] = 4 MB, reuses xb

  prep_all<<<dim3(9728), 256, 0, stream>>>(cosT, sinT, x, W_Q, W_K, W_V, W_O,
                                           csF, xb, Wt, WOt);
  gemm8p3<<<dim3((M / 128) * (NQKV / 384)), 512, 0, stream>>>(xb, x, Wt, QKV, VT, M, NQKV, C, cosT);
  rope_vtrans<<<dim3(6144), 256, 0, stream>>>(QKV, csF, VT, cosT);
  attn_fwd7<<<dim3(1024), 256, 0, stream>>>(QKV, VT, AO, csF, cosT, sinT);
  gemm8p<<<dim3((M / 128) * (C / 256)), 512, 0, stream>>>(AO, WOt, d_out, M, C, C, cosT);
}

// Round 33
// 194.175 us; speedup vs baseline: 1.0563x; 1.0001x over previous
//
#include <hip/hip_runtime.h>
#include <hip/hip_bf16.h>
#include <stdint.h>

typedef __bf16 bf16_4 __attribute__((ext_vector_type(4)));
typedef __bf16 bf16_8 __attribute__((ext_vector_type(8)));
typedef float f32x4 __attribute__((ext_vector_type(4)));

#define AS1 __attribute__((address_space(1)))
#define AS3 __attribute__((address_space(3)))

__device__ __forceinline__ void gload_lds16(const void* g, void* l) {
  __builtin_amdgcn_global_load_lds((const AS1 void*)g, (AS3 void*)l, 16, 0, 0);
}

// isb: device-side dtype probe. cos[0] == 1.0 exactly; f32 1.0 low halfword =
// 0x0000, packed bf16 (1.0,1.0) = 0x3F803F80 -> low halfword 0x3F80.
__device__ __forceinline__ bool is_bf16_mode(const void* cosT) {
  return ((*reinterpret_cast<const uint32_t*>(cosT)) & 0xFFFFu) == 0x3F80u;
}

// ---------------------------------------------------------------------------
// Fused prep: [0,512) cos/sin->f32; [512,4608) x->bf16 (f32 mode ONLY — in
// bf16 mode gemm1 reads x directly); [4608,9728) weight transpose+convert,
// VECTORIZED: 64x32 tiles, one 16B load + one 16B store per thread.
// ---------------------------------------------------------------------------
__global__ __launch_bounds__(256) void prep_all(const void* __restrict__ cosT,
                                                const void* __restrict__ sinT,
                                                const void* __restrict__ x,
                                                const void* __restrict__ WQ,
                                                const void* __restrict__ WK,
                                                const void* __restrict__ WV,
                                                const void* __restrict__ WO,
                                                float* __restrict__ csF,
                                                __bf16* __restrict__ xb,
                                                __bf16* __restrict__ Wt,
                                                __bf16* __restrict__ WOt) {
  const int blk = blockIdx.x, tid = threadIdx.x;
  const bool isb = is_bf16_mode(cosT);
  if (blk < 512) {                      // tables -> f32
    const int i = blk * 256 + tid;
    if (isb) {
      csF[i]          = (float)reinterpret_cast<const __bf16*>(cosT)[i];
      csF[131072 + i] = (float)reinterpret_cast<const __bf16*>(sinT)[i];
    } else {
      csF[i]          = reinterpret_cast<const float*>(cosT)[i];
      csF[131072 + i] = reinterpret_cast<const float*>(sinT)[i];
    }
    return;
  }
  if (blk < 4608) {                     // x -> bf16 (f32 mode only)
    if (isb) return;                    // bf16 mode: gemm reads x directly
    const int i = (blk - 512) * 256 + tid;
    const float4* s = reinterpret_cast<const float4*>(x);
    const float4 a = s[2 * i], c = s[2 * i + 1];
    __bf16 o[8] = {(__bf16)a.x, (__bf16)a.y, (__bf16)a.z, (__bf16)a.w,
                   (__bf16)c.x, (__bf16)c.y, (__bf16)c.z, (__bf16)c.w};
    reinterpret_cast<int4*>(xb)[i] = *reinterpret_cast<int4*>(o);
    return;
  }
  // weight transpose: tb in [0,5120) = (bx 0..159) x (by 0..31), 64x32 tile
  __shared__ __bf16 t[64][33];          // +1 pad: column reads stride 33 = CF
  const int tb = blk - 4608;
  const int bx = tb % 160, by = tb / 160;
  const void* src;
  __bf16* dst;
  int C, c0;
  if (bx < 64)      { src = WQ; dst = Wt;                        C = 2048; c0 = bx * 32; }
  else if (bx < 80) { src = WK; dst = Wt + (size_t)2048 * 2048;  C = 512;  c0 = (bx - 64) * 32; }
  else if (bx < 96) { src = WV; dst = Wt + (size_t)2560 * 2048;  C = 512;  c0 = (bx - 80) * 32; }
  else              { src = WO; dst = WOt;                       C = 2048; c0 = (bx - 96) * 32; }
  const int r0 = by * 64;
  // load: thread -> (row = tid>>2, colblk = (tid&3)*8), one 16B (bf16) or
  // 2x16B (f32) vector load, 8 LDS scalar writes
  {
    const int row = tid >> 2, cb = (tid & 3) * 8;
    bf16_8 v;
    if (isb) {
      v = *reinterpret_cast<const bf16_8*>(
          reinterpret_cast<const __bf16*>(src) + (size_t)(r0 + row) * C + c0 + cb);
    } else {
      const float* sp = reinterpret_cast<const float*>(src) + (size_t)(r0 + row) * C + c0 + cb;
      const float4 a = *reinterpret_cast<const float4*>(sp);
      const float4 b2 = *reinterpret_cast<const float4*>(sp + 4);
      v[0] = (__bf16)a.x;  v[1] = (__bf16)a.y;  v[2] = (__bf16)a.z;  v[3] = (__bf16)a.w;
      v[4] = (__bf16)b2.x; v[5] = (__bf16)b2.y; v[6] = (__bf16)b2.z; v[7] = (__bf16)b2.w;
    }
    #pragma unroll
    for (int k = 0; k < 8; ++k) t[row][cb + k] = v[k];
  }
  __syncthreads();
  // store: thread -> (out col j = tid>>3, row seg = (tid&7)*8), 8 LDS column
  // reads (stride 33, conflict-free) -> one 16B vector store
  {
    const int j = tid >> 3, seg = (tid & 7) * 8;
    bf16_8 v;
    #pragma unroll
    for (int k = 0; k < 8; ++k) v[k] = t[seg + k][j];
    *reinterpret_cast<bf16_8*>(dst + (size_t)(c0 + j) * 2048 + r0 + seg) = v;
  }
}

// ---------------------------------------------------------------------------
// GEMM A: 128x256 tile, BK=64, 8 waves, dbuf LDS (96KB), XOR-swizzle,
// 2 phases/K-tile, counted vmcnt + setprio. 1-D grid, bijective XCD swizzle.
// Output dtype per is_bf16_mode(cosRaw). Used for gemm2 (N=2048, grid 256).
// ---------------------------------------------------------------------------
__global__ __launch_bounds__(512) void gemm8p(const __bf16* __restrict__ A,
                                              const __bf16* __restrict__ Bt,
                                              void* __restrict__ Cv,
                                              int M, int N, int K,
                                              const void* __restrict__ cosRaw) {
  __shared__ __attribute__((aligned(16))) __bf16 As[2][128 * 64];
  __shared__ __attribute__((aligned(16))) __bf16 Bs[2][256 * 64];
  const int tid = threadIdx.x;
  const int lane = tid & 63, w = tid >> 6;
  const int wm = w >> 2, wn = w & 3;
  const int r = lane & 15, g = lane >> 4;
  const int q8 = gridDim.x >> 3;
  const int wg = (blockIdx.x & 7) * q8 + (blockIdx.x >> 3);
  const int gx = M >> 7;
  const int bm = (wg % gx) * 128, bn = (wg / gx) * 256;
  const bool isb = is_bf16_mode(cosRaw);
  const int NT = K >> 6;

  f32x4 acc[4][4] = {};

#define STA(kt, p, j)                                                              \
  {                                                                                \
    const int o_ = tid * 16 + (j) * 8192;                                          \
    const int row_ = o_ >> 7, blk_ = (o_ >> 4) & 7;                                \
    gload_lds16(A + (size_t)(bm + row_) * K + (kt) * 64 + ((blk_ ^ (row_ & 7)) << 3), \
                (char*)As[p] + o_);                                                \
  }
#define STB(kt, p, j)                                                              \
  {                                                                                \
    const int o_ = tid * 16 + (j) * 8192;                                          \
    const int rl_ = o_ >> 7, blk_ = (o_ >> 4) & 7;                                 \
    const int gr_ = ((rl_ >> 5) & 3) * 64 + ((rl_ >> 7) & 1) * 32 + (rl_ & 31);    \
    gload_lds16(Bt + (size_t)(bn + gr_) * K + (kt) * 64 + ((blk_ ^ (rl_ & 7)) << 3), \
                (char*)Bs[p] + o_);                                                \
  }

  STA(0, 0, 0); STA(0, 0, 1);
  STB(0, 0, 0); STB(0, 0, 1); STB(0, 0, 2); STB(0, 0, 3);
  asm volatile("s_waitcnt vmcnt(2)\ns_barrier" ::: "memory");

  for (int kt = 0; kt < NT; ++kt) {
    const int cur = kt & 1, nxt = cur ^ 1;
    const bool pf = (kt + 1 < NT);
    const char* Ac = (const char*)As[cur];
    const char* Bc = (const char*)Bs[cur];

    bf16_8 af[4][2], bf[2][2];
    #pragma unroll
    for (int m = 0; m < 4; ++m)
      #pragma unroll
      for (int kk = 0; kk < 2; ++kk) {
        const int row = wm * 64 + m * 16 + r;
        af[m][kk] = *reinterpret_cast<const bf16_8*>(
            Ac + row * 128 + (((kk * 4 + g) ^ (row & 7)) << 4));
      }
    #pragma unroll
    for (int n = 0; n < 2; ++n)
      #pragma unroll
      for (int kk = 0; kk < 2; ++kk) {
        const int rl = wn * 32 + n * 16 + r;
        bf[n][kk] = *reinterpret_cast<const bf16_8*>(
            Bc + rl * 128 + (((kk * 4 + g) ^ (rl & 7)) << 4));
      }
    if (pf) { STA(kt + 1, nxt, 0); STA(kt + 1, nxt, 1); STB(kt + 1, nxt, 0); }
    __builtin_amdgcn_s_barrier();
    __builtin_amdgcn_s_setprio(1);
    #pragma unroll
    for (int kk = 0; kk < 2; ++kk)
      #pragma unroll
      for (int m = 0; m < 4; ++m)
        #pragma unroll
        for (int n = 0; n < 2; ++n)
          acc[m][n] = __builtin_amdgcn_mfma_f32_16x16x32_bf16(af[m][kk], bf[n][kk], acc[m][n], 0, 0, 0);
    __builtin_amdgcn_s_setprio(0);
    if (pf) asm volatile("s_waitcnt vmcnt(3)\ns_barrier" ::: "memory");
    else    asm volatile("s_waitcnt vmcnt(0)\ns_barrier" ::: "memory");

    bf16_8 bg[2][2];
    #pragma unroll
    for (int n = 0; n < 2; ++n)
      #pragma unroll
      for (int kk = 0; kk < 2; ++kk) {
        const int rl = 128 + wn * 32 + n * 16 + r;
        bg[n][kk] = *reinterpret_cast<const bf16_8*>(
            Bc + rl * 128 + (((kk * 4 + g) ^ (rl & 7)) << 4));
      }
    if (pf) { STB(kt + 1, nxt, 1); STB(kt + 1, nxt, 2); STB(kt + 1, nxt, 3); }
    __builtin_amdgcn_s_barrier();
    __builtin_amdgcn_s_setprio(1);
    #pragma unroll
    for (int kk = 0; kk < 2; ++kk)
      #pragma unroll
      for (int m = 0; m < 4; ++m)
        #pragma unroll
        for (int n = 0; n < 2; ++n)
          acc[m][n + 2] = __builtin_amdgcn_mfma_f32_16x16x32_bf16(af[m][kk], bg[n][kk], acc[m][n + 2], 0, 0, 0);
    __builtin_amdgcn_s_setprio(0);
    if (pf) asm volatile("s_waitcnt vmcnt(2)\ns_barrier" ::: "memory");
    else    asm volatile("s_waitcnt vmcnt(0)\ns_barrier" ::: "memory");
  }
#undef STA
#undef STB

  #pragma unroll
  for (int m = 0; m < 4; ++m)
    #pragma unroll
    for (int n = 0; n < 4; ++n)
      #pragma unroll
      for (int j = 0; j < 4; ++j) {
        const int row = bm + wm * 64 + m * 16 + g * 4 + j;
        const int col = bn + wn * 64 + n * 16 + r;
        const float v = acc[m][n][j];
        if (isb) reinterpret_cast<__bf16*>(Cv)[(size_t)row * N + col] = (__bf16)v;
        else     reinterpret_cast<float*>(Cv)[(size_t)row * N + col] = v;
      }
}

// ---------------------------------------------------------------------------
// GEMM B: 128x384 tile for N=3072 -> grid 256 = 1 block/CU exactly.
// 3 phases/K-tile, counted-vmcnt ledger. A operand: bf16 mode reads x
// directly (Araw). V outputs (col >= 2560, bf16 mode) go directly to VT
// in transposed layout (packed 8B store); f32 mode keeps the old path.
// ---------------------------------------------------------------------------
__global__ __launch_bounds__(512) void gemm8p3(const __bf16* __restrict__ Acvt,
                                               const void* __restrict__ Araw,
                                               const __bf16* __restrict__ Bt,
                                               __bf16* __restrict__ Cv,
                                               __bf16* __restrict__ vtOut,
                                               int M, int N, int K,
                                               const void* __restrict__ cosRaw) {
  __shared__ __attribute__((aligned(16))) __bf16 As[2][128 * 64];
  __shared__ __attribute__((aligned(16))) __bf16 Bs[2][384 * 64];
  const int tid = threadIdx.x;
  const int lane = tid & 63, w = tid >> 6;
  const int wm = w >> 2, wn = w & 3;
  const int r = lane & 15, g = lane >> 4;
  const int q8 = gridDim.x >> 3;
  const int wg = (blockIdx.x & 7) * q8 + (blockIdx.x >> 3);
  const int gx = M >> 7;
  const int bm = (wg % gx) * 128, bn = (wg / gx) * 384;
  const int NT = K >> 6;
  const bool isb = is_bf16_mode(cosRaw);
  const __bf16* A = isb ? (const __bf16*)Araw : Acvt;

  f32x4 acc[4][6] = {};

#define STA3(kt, p, j)                                                             \
  {                                                                                \
    const int o_ = tid * 16 + (j) * 8192;                                          \
    const int row_ = o_ >> 7, blk_ = (o_ >> 4) & 7;                                \
    gload_lds16(A + (size_t)(bm + row_) * K + (kt) * 64 + ((blk_ ^ (row_ & 7)) << 3), \
                (char*)As[p] + o_);                                                \
  }
#define STB3(kt, p, j)                                                             \
  {                                                                                \
    const int o_ = tid * 16 + (j) * 8192;                                          \
    const int rl_ = o_ >> 7, blk_ = (o_ >> 4) & 7;                                 \
    const int gr_ = ((rl_ & 127) >> 5) * 96 + (rl_ >> 7) * 32 + (rl_ & 31);        \
    gload_lds16(Bt + (size_t)(bn + gr_) * K + (kt) * 64 + ((blk_ ^ (rl_ & 7)) << 3), \
                (char*)Bs[p] + o_);                                                \
  }

  STA3(0, 0, 0); STA3(0, 0, 1);
  STB3(0, 0, 0); STB3(0, 0, 1); STB3(0, 0, 2);
  STB3(0, 0, 3); STB3(0, 0, 4); STB3(0, 0, 5);
  asm volatile("s_waitcnt vmcnt(4)\ns_barrier" ::: "memory");

  for (int kt = 0; kt < NT; ++kt) {
    const int cur = kt & 1, nxt = cur ^ 1;
    const bool pf = (kt + 1 < NT);
    const char* Ac = (const char*)As[cur];
    const char* Bc = (const char*)Bs[cur];
    bf16_8 af[4][2];

    // ---- phase A: all A-frags + B seg0 (n = 0,1) ----
    {
      #pragma unroll
      for (int m = 0; m < 4; ++m)
        #pragma unroll
        for (int kk = 0; kk < 2; ++kk) {
          const int row = wm * 64 + m * 16 + r;
          af[m][kk] = *reinterpret_cast<const bf16_8*>(
              Ac + row * 128 + (((kk * 4 + g) ^ (row & 7)) << 4));
        }
      bf16_8 bf[2][2];
      #pragma unroll
      for (int n = 0; n < 2; ++n)
        #pragma unroll
        for (int kk = 0; kk < 2; ++kk) {
          const int rl = wn * 32 + n * 16 + r;
          bf[n][kk] = *reinterpret_cast<const bf16_8*>(
              Bc + rl * 128 + (((kk * 4 + g) ^ (r & 7)) << 4));
        }
      if (pf) { STA3(kt + 1, nxt, 0); STA3(kt + 1, nxt, 1); STB3(kt + 1, nxt, 0); }
      __builtin_amdgcn_s_barrier();
      __builtin_amdgcn_s_setprio(1);
      #pragma unroll
      for (int kk = 0; kk < 2; ++kk)
        #pragma unroll
        for (int m = 0; m < 4; ++m)
          #pragma unroll
          for (int n = 0; n < 2; ++n)
            acc[m][n] = __builtin_amdgcn_mfma_f32_16x16x32_bf16(af[m][kk], bf[n][kk], acc[m][n], 0, 0, 0);
      __builtin_amdgcn_s_setprio(0);
      if (pf) asm volatile("s_waitcnt vmcnt(5)\ns_barrier" ::: "memory");
      else    asm volatile("s_waitcnt vmcnt(0)\ns_barrier" ::: "memory");
    }

    // ---- phase B: B seg1 (n = 2,3) ----
    {
      bf16_8 bf[2][2];
      #pragma unroll
      for (int n = 0; n < 2; ++n)
        #pragma unroll
        for (int kk = 0; kk < 2; ++kk) {
          const int rl = 128 + wn * 32 + n * 16 + r;
          bf[n][kk] = *reinterpret_cast<const bf16_8*>(
              Bc + rl * 128 + (((kk * 4 + g) ^ (r & 7)) << 4));
        }
      if (pf) { STB3(kt + 1, nxt, 1); STB3(kt + 1, nxt, 2); }
      __builtin_amdgcn_s_barrier();
      __builtin_amdgcn_s_setprio(1);
      #pragma unroll
      for (int kk = 0; kk < 2; ++kk)
        #pragma unroll
        for (int m = 0; m < 4; ++m)
          #pragma unroll
          for (int n = 0; n < 2; ++n)
            acc[m][n + 2] = __builtin_amdgcn_mfma_f32_16x16x32_bf16(af[m][kk], bf[n][kk], acc[m][n + 2], 0, 0, 0);
      __builtin_amdgcn_s_setprio(0);
      if (pf) asm volatile("s_waitcnt vmcnt(5)\ns_barrier" ::: "memory");
      else    asm volatile("s_waitcnt vmcnt(0)\ns_barrier" ::: "memory");
    }

    // ---- phase C: B seg2 (n = 4,5) ----
    {
      bf16_8 bf[2][2];
      #pragma unroll
      for (int n = 0; n < 2; ++n)
        #pragma unroll
        for (int kk = 0; kk < 2; ++kk) {
          const int rl = 256 + wn * 32 + n * 16 + r;
          bf[n][kk] = *reinterpret_cast<const bf16_8*>(
              Bc + rl * 128 + (((kk * 4 + g) ^ (r & 7)) << 4));
        }
      if (pf) { STB3(kt + 1, nxt, 3); STB3(kt + 1, nxt, 4); STB3(kt + 1, nxt, 5); }
      __builtin_amdgcn_s_barrier();
      __builtin_amdgcn_s_setprio(1);
      #pragma unroll
      for (int kk = 0; kk < 2; ++kk)
        #pragma unroll
        for (int m = 0; m < 4; ++m)
          #pragma unroll
          for (int n = 0; n < 2; ++n)
            acc[m][n + 4] = __builtin_amdgcn_mfma_f32_16x16x32_bf16(af[m][kk], bf[n][kk], acc[m][n + 4], 0, 0, 0);
      __builtin_amdgcn_s_setprio(0);
      if (pf) asm volatile("s_waitcnt vmcnt(4)\ns_barrier" ::: "memory");
      else    asm volatile("s_waitcnt vmcnt(0)\ns_barrier" ::: "memory");
    }
  }
#undef STA3
#undef STB3

  #pragma unroll
  for (int m = 0; m < 4; ++m)
    #pragma unroll
    for (int n = 0; n < 6; ++n) {
      const int row0 = bm + wm * 64 + m * 16 + g * 4;   // 4-aligned, +j rows
      const int col  = bn + wn * 96 + n * 16 + r;
      if (isb && col >= 2560) {
        // V output -> VT[b][kvh][d][t0..t0+3], one packed 8B store
        const int vcol = col - 2560;                    // 0..511 = kvh*128+d
        const int bb = row0 >> 11;                      // batch index
        const int t0 = row0 & 2047;                     // 4-aligned
        bf16_4 pk;
        #pragma unroll
        for (int j = 0; j < 4; ++j) pk[j] = (__bf16)acc[m][n][j];
        *reinterpret_cast<bf16_4*>(
            &vtOut[((size_t)bb * 512 + vcol) * 2048 + t0]) = pk;
      } else {
        #pragma unroll
        for (int j = 0; j < 4; ++j)
          Cv[(size_t)(row0 + j) * N + col] = (__bf16)acc[m][n][j];
      }
    }
}

// ---------------------------------------------------------------------------
// K-only RoPE/RMS (blocks [0,4096), heads 16..19) + V transpose (blocks
// [4096,6144), f32 mode only). Q rope is fused into attn's Q load.
// ---------------------------------------------------------------------------
__global__ __launch_bounds__(256) void rope_vtrans(__bf16* __restrict__ qkv,
                                                   const float* __restrict__ csF,
                                                   __bf16* __restrict__ vt,
                                                   const void* __restrict__ cosRaw) {
  const int blk = blockIdx.x, tid = threadIdx.x;
  if (blk < 4096) {                         // K RoPE + RMS (heads 16..19)
    const int gw = blk * 4 + (tid >> 6);    // 0..16383
    const int lane = tid & 63;
    const int head = 16 + (gw & 3);
    const int m = gw >> 2;                  // 0..4095
    const int t = m & 2047;
    __bf16* p = qkv + (size_t)m * 3072 + head * 128;
    const float x1 = (float)p[lane];
    const float x2 = (float)p[lane + 64];
    const float c = csF[t * 64 + lane];
    const float s = csF[131072 + t * 64 + lane];
    const float y1 = x1 * c + x2 * s;
    const float y2 = x2 * c - x1 * s;
    float ss = y1 * y1 + y2 * y2;
    #pragma unroll
    for (int mk = 32; mk >= 1; mk >>= 1) ss += __shfl_xor(ss, mk, 64);
    const float inv = rsqrtf(ss * (1.0f / 128.0f) + 1.1920929e-7f);
    p[lane] = (__bf16)(y1 * inv);
    p[lane + 64] = (__bf16)(y2 * inv);
    return;
  }
  if (is_bf16_mode(cosRaw)) return;         // bf16 mode: VT already written
  // V transpose (f32 mode): vb in [0,2048) = z(2) x y(16) x x(64)
  __shared__ __bf16 t[32][33];
  const int vb = blk - 4096;
  const int z = vb >> 10, rem = vb & 1023;
  const int x = rem & 63, y = rem >> 6;
  const int tx = tid & 31, ty = tid >> 5;
  const int t0 = x * 32, c0 = y * 32;
  #pragma unroll
  for (int i = 0; i < 32; i += 8)
    t[ty + i][tx] = qkv[(size_t)(z * 2048 + t0 + ty + i) * 3072 + 2560 + c0 + tx];
  __syncthreads();
  #pragma unroll
  for (int i = 0; i < 32; i += 8)
    vt[(size_t)(z * 512 + c0 + ty + i) * 2048 + t0 + tx] = t[tx][ty + i];
}

// ---------------------------------------------------------------------------
// GQA causal flash attention v9 = v7.5 + T4: double-buffered K/V (LDS 72KB,
// 2 blocks/CU) with counted vmcnt. STAGE(kt+1) issues before compute(kt);
// steady-state waits vmcnt(8) (= the 8 in-flight prefetch loads) instead of
// draining to 0. Raw s_barrier (memory-clobbered) so the compiler cannot
// re-insert the drain. Everything else byte-identical to the verified v7.5.
// Hazards: barrier1 separates compute(kt-1) reads of buf B from STAGE(kt+1)
// writes to B; vmcnt(8)+barrier2 ensures tile kt landed block-wide; Pl is
// per-wave (no cross-wave dep).
// ---------------------------------------------------------------------------
__global__ __launch_bounds__(256) void attn_fwd9(const __bf16* __restrict__ qkv,
                                                 const __bf16* __restrict__ vt,
                                                 __bf16* __restrict__ out,
                                                 const float* __restrict__ csF,
                                                 const void* __restrict__ cosRawT,
                                                 const void* __restrict__ sinRawT) {
  __shared__ __attribute__((aligned(16))) __bf16 Kl[2][64 * 128];
  __shared__ __attribute__((aligned(16))) __bf16 Vl[2][128 * 64];
  __shared__ __attribute__((aligned(16))) __bf16 Pl[4][16][64];

  const int tid = threadIdx.x, lane = tid & 63, w = tid >> 6;
  const int r = lane & 15, g = lane >> 4;
  const int lid = blockIdx.x;
  const int grp = lid & 7, inner = lid >> 3;   // inner 0..127
  const int b = grp >> 2, kvh = grp & 3;
  const int h = kvh * 4 + (inner & 3);
  const int qt = 31 - (inner >> 2);            // heaviest first (verified best)
  const int qpos = qt * 64 + w * 16 + r;       // loop-invariant
  const __bf16* Kbase = qkv + (size_t)(b * 2048) * 3072 + 2048 + kvh * 128;
  const __bf16* Vbase = vt + (size_t)((b * 4 + kvh) * 128) * 2048;

#define STAGE(kt, p)                                                            \
  {                                                                             \
    _Pragma("unroll")                                                           \
    for (int i_ = 0; i_ < 4; ++i_) {                                            \
      const int o_ = tid * 16 + i_ * 4096;                                      \
      const int krow_ = o_ >> 8;                                                \
      const int jj_ = (o_ >> 4) & 15;                                           \
      const int gj_ = (jj_ & 8) | ((jj_ ^ krow_) & 7);                          \
      gload_lds16(Kbase + (size_t)((kt) * 64 + krow_) * 3072 + gj_ * 8,         \
                  (char*)Kl[p] + o_);                                           \
      const int d_ = o_ >> 7;                                                   \
      const int j2_ = (o_ >> 4) & 7;                                            \
      const int g2_ = j2_ ^ (d_ & 7);                                           \
      gload_lds16(Vbase + (size_t)d_ * 2048 + (kt) * 64 + g2_ * 8,              \
                  (char*)Vl[p] + o_);                                           \
    }                                                                           \
  }

#define ATTN_TILE(kt, p, MASKED)                                                \
  {                                                                             \
    const char* Kc = (const char*)Kl[p];                                        \
    const char* Vc = (const char*)Vl[p];                                        \
    f32x4 sacc[4] = {};                                                         \
    _Pragma("unroll")                                                           \
    for (int kb = 0; kb < 4; ++kb) {                                            \
      const int jj = kb * 4 + g;                                                \
      const int jp = (jj & 8) | ((jj ^ (r & 7)) & 7);                           \
      _Pragma("unroll")                                                         \
      for (int n = 0; n < 4; ++n) {                                             \
        const bf16_8 kf = *reinterpret_cast<const bf16_8*>(                     \
            Kc + (n * 16 + r) * 256 + jp * 16);                                 \
        sacc[n] = __builtin_amdgcn_mfma_f32_16x16x32_bf16(kf, qf[kb], sacc[n], 0, 0, 0); \
      }                                                                         \
    }                                                                           \
    float p_[4][4];                                                             \
    float pm = -1e30f;                                                          \
    _Pragma("unroll")                                                           \
    for (int n = 0; n < 4; ++n)                                                 \
      _Pragma("unroll")                                                         \
      for (int j = 0; j < 4; ++j) {                                             \
        float sv = sacc[n][j];                                                  \
        if (MASKED && ((kt) * 64 + n * 16 + g * 4 + j > qpos)) sv = -1e30f;     \
        p_[n][j] = sv;                                                          \
        pm = fmaxf(pm, sv);                                                     \
      }                                                                         \
    pm = fmaxf(pm, __shfl_xor(pm, 16, 64));                                     \
    pm = fmaxf(pm, __shfl_xor(pm, 32, 64));                                     \
    float mn = mst;                                                             \
    if (!__all(pm - mst <= 12.0f)) {                                            \
      mn = fmaxf(mst, pm);                                                      \
      const float alpha = exp2f(mst - mn);                                      \
      mst = mn;                                                                 \
      lst *= alpha;                                                             \
      float av[4];                                                              \
      _Pragma("unroll")                                                         \
      for (int j = 0; j < 4; ++j) av[j] = __shfl(alpha, g * 4 + j, 64);         \
      _Pragma("unroll")                                                         \
      for (int dt = 0; dt < 8; ++dt)                                            \
        _Pragma("unroll")                                                       \
        for (int j = 0; j < 4; ++j) accO[dt][j] *= av[j];                       \
    }                                                                           \
    float rs = 0.0f;                                                            \
    _Pragma("unroll")                                                           \
    for (int n = 0; n < 4; ++n)                                                 \
      _Pragma("unroll")                                                         \
      for (int j = 0; j < 4; ++j) {                                             \
        p_[n][j] = exp2f(p_[n][j] - mn);                                        \
        rs += p_[n][j];                                                         \
      }                                                                         \
    rs += __shfl_xor(rs, 16, 64);                                               \
    rs += __shfl_xor(rs, 32, 64);                                               \
    lst += rs;                                                                  \
    _Pragma("unroll")                                                           \
    for (int n = 0; n < 4; ++n) {                                               \
      bf16_4 pk;                                                                \
      _Pragma("unroll")                                                         \
      for (int j = 0; j < 4; ++j) pk[j] = (__bf16)p_[n][j];                     \
      const int blk = 2 * n + (g >> 1);                                         \
      char* pw = plw + r * 128 + ((blk ^ (r & 7)) << 4) + (g & 1) * 8;          \
      *reinterpret_cast<bf16_4*>(pw) = pk;                                      \
    }                                                                           \
    _Pragma("unroll")                                                           \
    for (int half = 0; half < 2; ++half) {                                      \
      const bf16_8 pa = *reinterpret_cast<const bf16_8*>(                       \
          plw + r * 128 + (((half * 4 + g) ^ (r & 7)) << 4));                   \
      _Pragma("unroll")                                                         \
      for (int dt = 0; dt < 8; ++dt) {                                          \
        const int d = dt * 16 + r;                                              \
        const bf16_8 vf = *reinterpret_cast<const bf16_8*>(                     \
            Vc + d * 128 + ((half * 4 + g) ^ (d & 7)) * 16);                    \
        accO[dt] = __builtin_amdgcn_mfma_f32_16x16x32_bf16(pa, vf, accO[dt], 0, 0, 0); \
      }                                                                         \
    }                                                                           \
  }

  // --- Q fragments: raw load + fused RoPE + RMS + pre-scale ---
  bf16_8 qf[4];
  {
    const int trow = qt * 64 + w * 16 + r;     // position within batch
    const __bf16* qp = qkv + (size_t)(b * 2048 + trow) * 3072 + h * 128 + g * 8;
    bf16_8 rq[4];
    #pragma unroll
    for (int kb = 0; kb < 4; ++kb) rq[kb] = *reinterpret_cast<const bf16_8*>(qp + kb * 32);
    // rope tables: vectorized loads (bf16_8 in bf16 mode, float4 pairs in f32).
    float cv[16], sv[16];
    if (is_bf16_mode(cosRawT)) {
      const __bf16* cb = reinterpret_cast<const __bf16*>(cosRawT) + (size_t)trow * 64 + g * 8;
      const __bf16* sb = reinterpret_cast<const __bf16*>(sinRawT) + (size_t)trow * 64 + g * 8;
      const bf16_8 clo = *reinterpret_cast<const bf16_8*>(cb);
      const bf16_8 chi = *reinterpret_cast<const bf16_8*>(cb + 32);
      const bf16_8 slo = *reinterpret_cast<const bf16_8*>(sb);
      const bf16_8 shi = *reinterpret_cast<const bf16_8*>(sb + 32);
      #pragma unroll
      for (int i = 0; i < 8; ++i) {
        cv[i] = (float)clo[i];  cv[8 + i] = (float)chi[i];
        sv[i] = (float)slo[i];  sv[8 + i] = (float)shi[i];
      }
    } else {
      const float* cb = csF + (size_t)trow * 64 + g * 8;
      const float* sb = csF + 131072 + (size_t)trow * 64 + g * 8;
      #pragma unroll
      for (int i = 0; i < 2; ++i) {
        const float4 c0 = *reinterpret_cast<const float4*>(cb + i * 4);
        const float4 c1 = *reinterpret_cast<const float4*>(cb + 32 + i * 4);
        const float4 s0 = *reinterpret_cast<const float4*>(sb + i * 4);
        const float4 s1 = *reinterpret_cast<const float4*>(sb + 32 + i * 4);
        cv[i * 4 + 0] = c0.x; cv[i * 4 + 1] = c0.y; cv[i * 4 + 2] = c0.z; cv[i * 4 + 3] = c0.w;
        cv[8 + i * 4 + 0] = c1.x; cv[8 + i * 4 + 1] = c1.y; cv[8 + i * 4 + 2] = c1.z; cv[8 + i * 4 + 3] = c1.w;
        sv[i * 4 + 0] = s0.x; sv[i * 4 + 1] = s0.y; sv[i * 4 + 2] = s0.z; sv[i * 4 + 3] = s0.w;
        sv[8 + i * 4 + 0] = s1.x; sv[8 + i * 4 + 1] = s1.y; sv[8 + i * 4 + 2] = s1.z; sv[8 + i * 4 + 3] = s1.w;
      }
    }
    float y[4][8];
    float ss = 0.0f;
    #pragma unroll
    for (int i = 0; i < 8; ++i) {
      const float c0 = cv[i],     s0 = sv[i];        // d in [0,32)+g8
      const float c1 = cv[8 + i], s1 = sv[8 + i];    // d in [32,64)+g8
      const float xa0 = (float)rq[0][i], xb0 = (float)rq[2][i];   // pair (d, d+64)
      const float xa1 = (float)rq[1][i], xb1 = (float)rq[3][i];
      y[0][i] = xa0 * c0 + xb0 * s0;
      y[2][i] = xb0 * c0 - xa0 * s0;
      y[1][i] = xa1 * c1 + xb1 * s1;
      y[3][i] = xb1 * c1 - xa1 * s1;
      ss += y[0][i] * y[0][i] + y[1][i] * y[1][i] + y[2][i] * y[2][i] + y[3][i] * y[3][i];
    }
    ss += __shfl_xor(ss, 16, 64);
    ss += __shfl_xor(ss, 32, 64);
    const float inv = rsqrtf(ss * (1.0f / 128.0f) + 1.1920929e-7f) * 0.12751743f;
    #pragma unroll
    for (int kb = 0; kb < 4; ++kb)
      #pragma unroll
      for (int i = 0; i < 8; ++i) qf[kb][i] = (__bf16)(y[kb][i] * inv);
  }

  char* const plw = (char*)Pl + w * 2048;
  f32x4 accO[8] = {};
  float mst = -1e30f, lst = 0.0f;

  // T4 pipeline: prefetch tile kt+1 while computing kt; counted vmcnt.
  STAGE(0, 0);
  for (int kt = 0; kt < qt; ++kt) {
    const int cur = kt & 1;
    asm volatile("s_barrier" ::: "memory");          // all done reading buf cur^1 (tile kt-1)
    STAGE(kt + 1, cur ^ 1);                          // prefetch next tile
    asm volatile("s_waitcnt vmcnt(8)" ::: "memory"); // my tile-kt loads landed
    asm volatile("s_barrier" ::: "memory");          // everyone's tile-kt loads landed
    ATTN_TILE(kt, cur, false);
  }
  {
    const int cur = qt & 1;
    asm volatile("s_barrier" ::: "memory");
    asm volatile("s_waitcnt vmcnt(0)" ::: "memory");
    asm volatile("s_barrier" ::: "memory");
    ATTN_TILE(qt, cur, true);                        // diagonal, masked
  }

  // --- epilogue: normalize + store ---
  float lv[4];
  #pragma unroll
  for (int j = 0; j < 4; ++j) lv[j] = 1.0f / __shfl(lst, g * 4 + j, 64);
  #pragma unroll
  for (int dt = 0; dt < 8; ++dt)
    #pragma unroll
    for (int j = 0; j < 4; ++j) {
      const int t = qt * 64 + w * 16 + g * 4 + j;
      out[(size_t)(b * 2048 + t) * 2048 + h * 128 + dt * 16 + r] = (__bf16)(accO[dt][j] * lv[j]);
    }
#undef ATTN_TILE
#undef STAGE
}

// ---------------------------------------------------------------------------
extern "C" void kernel_launch(void* const* d_in, const int* in_sizes, int n_in,
                              void* d_out, int out_size, void* d_ws, size_t ws_size,
                              hipStream_t stream) {
  const void* x    = d_in[0];
  const void* cosT = d_in[1];
  const void* sinT = d_in[2];
  const void* W_Q  = d_in[3];
  const void* W_K  = d_in[4];
  const void* W_V  = d_in[5];
  const void* W_O  = d_in[6];

  const int B = 2, T = 2048, C = 2048;
  const int M = B * T;        // 4096
  const int NQKV = 3072;

  char* ws = (char*)d_ws;
  ws += 256;                                     // (reserved, keeps prior layout)
  float*  csF  = (float*)ws;                     ws += (size_t)2 * 131072 * 4;   // 1 MB
  __bf16* xb   = (__bf16*)ws;                    ws += (size_t)M * C * 2;        // 16.8 MB
  __bf16* Wt   = (__bf16*)ws;                    ws += (size_t)NQKV * C * 2;     // 12.6 MB
  __bf16* WOt  = (__bf16*)ws;                    ws += (size_t)C * C * 2;        // 8.4 MB
  __bf16* QKV  = (__bf16*)ws;                    ws += (size_t)M * NQKV * 2;     // 25.2 MB
  __bf16* AO   = (__bf16*)ws;                    ws += (size_t)M * C * 2;        // 16.8 MB
  __bf16* VT   = xb;                             // [2][4][128][2048] = 4 MB, reuses xb

  prep_all<<<dim3(9728), 256, 0, stream>>>(cosT, sinT, x, W_Q, W_K, W_V, W_O,
                                           csF, xb, Wt, WOt);
  gemm8p3<<<dim3((M / 128) * (NQKV / 384)), 512, 0, stream>>>(xb, x, Wt, QKV, VT, M, NQKV, C, cosT);
  rope_vtrans<<<dim3(6144), 256, 0, stream>>>(QKV, csF, VT, cosT);
  attn_fwd9<<<dim3(1024), 256, 0, stream>>>(QKV, VT, AO, csF, cosT, sinT);
  gemm8p<<<dim3((M / 128) * (C / 256)), 512, 0, stream>>>(AO, WOt, d_out, M, C, C, cosT);
}